// Round 26
// baseline (230.510 us; speedup 1.0000x reference)
//
#include <hip/hip_runtime.h>
#include <hip/hip_bf16.h>
#include <math.h>

#define SEQ   2048
#define HDIM  1024
#define NH    16
#define NKV   4
#define DHEAD 64
#define TOPK  128

typedef __attribute__((ext_vector_type(8))) short short8;
typedef __attribute__((ext_vector_type(4))) float f32x4;

__device__ inline short f2bf_bits(float x) {          // RTN-even f32 -> bf16
  unsigned u = __float_as_uint(x);
  unsigned r = (u + 0x7FFFu + ((u >> 16) & 1u)) >> 16;
  return (short)r;
}
__device__ inline float bf2f(short s) {
  return __uint_as_float(((unsigned)(unsigned short)s) << 16);
}
__device__ inline void split3(float x, short& h, short& m, short& l) {
  h = f2bf_bits(x);
  float r1 = x - bf2f(h);
  m = f2bf_bits(r1);
  l = f2bf_bits(r1 - bf2f(m));
}

// ---- fused conversions: one dispatch, segmented grid -----------------------
__global__ __launch_bounds__(256) void conv_all(
    const float* __restrict__ hs, const float* __restrict__ Wq,
    const float* __restrict__ Wik, const float* __restrict__ Wiw,
    const float* __restrict__ Wk, const float* __restrict__ Wv,
    short* __restrict__ A_cat, short* __restrict__ Wh, short* __restrict__ Wl,
    short* __restrict__ Wkv) {
  int bb = blockIdx.x;
  int t = threadIdx.x;
  if (bb < 2048) {                          // hs split -> concat rows
    int i = bb * 256 + t;
    float4 v = *(const float4*)(hs + (long)i * 4);
    int r = i >> 8, c = (i & 255) * 4;
    short4 hv, lv;
    short h0 = f2bf_bits(v.x), h1 = f2bf_bits(v.y);
    short h2 = f2bf_bits(v.z), h3 = f2bf_bits(v.w);
    hv.x = h0; hv.y = h1; hv.z = h2; hv.w = h3;
    lv.x = f2bf_bits(v.x - bf2f(h0)); lv.y = f2bf_bits(v.y - bf2f(h1));
    lv.z = f2bf_bits(v.z - bf2f(h2)); lv.w = f2bf_bits(v.w - bf2f(h3));
    *(short4*)&A_cat[(long)r * 2048 + c] = hv;
    *(short4*)&A_cat[(long)r * 2048 + 1024 + c] = lv;
    return;
  }
  const float* src; short *dhi, *dlo; int i;
  if (bb < 3072)      { src = Wq;  dhi = Wh; dlo = Wl;
                        i = (bb - 2048) * 256 + t; }
  else if (bb < 3136) { src = Wik; dhi = Wh + (long)1024 * 1024;
                        dlo = Wl + (long)1024 * 1024;
                        i = (bb - 3072) * 256 + t; }
  else if (bb < 3152) { src = Wiw; dhi = Wh + (long)1088 * 1024;
                        dlo = Wl + (long)1088 * 1024;
                        i = (bb - 3136) * 256 + t; }
  else if (bb < 3408) { src = Wk;  dhi = Wkv; dlo = nullptr;
                        i = (bb - 3152) * 256 + t; }
  else                { src = Wv;  dhi = Wkv + (long)256 * 1024; dlo = nullptr;
                        i = (bb - 3408) * 256 + t; }
  float4 v = *(const float4*)(src + (long)i * 4);
  short4 hv;
  short h0 = f2bf_bits(v.x), h1 = f2bf_bits(v.y);
  short h2 = f2bf_bits(v.z), h3 = f2bf_bits(v.w);
  hv.x = h0; hv.y = h1; hv.z = h2; hv.w = h3;
  *(short4*)&dhi[(long)i * 4] = hv;
  if (dlo) {
    short4 lv;
    lv.x = f2bf_bits(v.x - bf2f(h0)); lv.y = f2bf_bits(v.y - bf2f(h1));
    lv.z = f2bf_bits(v.z - bf2f(h2)); lv.w = f2bf_bits(v.w - bf2f(h3));
    *(short4*)&dlo[(long)i * 4] = lv;
  }
}

// ---- fused projection GEMM: BM=64, BN=64, grid (26, 32) = 832 blocks -------
// __launch_bounds__(256,8): force VGPR<=64 -> 8 waves/SIMD capacity.
__global__ __launch_bounds__(256, 8) void gemm_all(
    const short* __restrict__ A_cat, const short* __restrict__ Wh,
    const short* __restrict__ Wl, const short* __restrict__ Wkv,
    const float* __restrict__ bq, const float* __restrict__ bik,
    const float* __restrict__ biw, const float* __restrict__ bk,
    const float* __restrict__ bv, float* __restrict__ qb,
    float* __restrict__ ikb, float* __restrict__ wb, float* __restrict__ kb,
    float* __restrict__ vb) {
  __shared__ short Als[64 * 64] __attribute__((aligned(16)));
  __shared__ short Bls[64 * 64] __attribute__((aligned(16)));
  int bx = blockIdx.x;
  bool sens = bx < 18;
  int n0 = (sens ? bx : bx - 18) * 64;
  int m0 = blockIdx.y * 64;
  int Nrows = sens ? 1104 : 512;
  int nterm = sens ? 3 : 1;
  int tid = threadIdx.x;
  int lane = tid & 63, wid = tid >> 6;
  int wm = (wid >> 1) * 32, wn = (wid & 1) * 32;   // wave: 32x32 output
  int lr = lane & 15, kg = lane >> 4;
  int arow = tid >> 2, aseg4 = tid & 3;
  int abase = arow * 64 + aseg4 * 16;
  int aswz = (arow & 7) * 8;
  bool bok = (n0 + arow) < Nrows;

  f32x4 acc[2][2] = {};
  for (int term = 0; term < nterm; ++term) {
    const short* Ab = A_cat + (term == 1 ? 1024 : 0);
    const short* Bb = sens ? (term == 2 ? Wl : Wh) : Wkv;
    const short* aseg = Ab + (long)(m0 + arow) * 2048 + aseg4 * 16;
    const short* bseg = Bb + (long)(n0 + arow) * 1024 + aseg4 * 16;
    short8 a0, a1, b0, b1;
    a0 = *(const short8*)(aseg);
    a1 = *(const short8*)(aseg + 8);
    b0 = bok ? *(const short8*)(bseg) : short8{};
    b1 = bok ? *(const short8*)(bseg + 8) : short8{};
    for (int t = 0; t < 16; ++t) {
      __syncthreads();
      *(short8*)&Als[abase ^ aswz] = a0;
      *(short8*)&Als[(abase + 8) ^ aswz] = a1;
      *(short8*)&Bls[abase ^ aswz] = b0;
      *(short8*)&Bls[(abase + 8) ^ aswz] = b1;
      __syncthreads();
      if (t + 1 < 16) {
        const short* an = aseg + (t + 1) * 64;
        const short* bn = bseg + (t + 1) * 64;
        a0 = *(const short8*)(an);
        a1 = *(const short8*)(an + 8);
        b0 = bok ? *(const short8*)(bn) : short8{};
        b1 = bok ? *(const short8*)(bn + 8) : short8{};
      }
#pragma unroll
      for (int kk = 0; kk < 2; ++kk) {
        short8 af[2], bf[2];
#pragma unroll
        for (int f = 0; f < 2; ++f) {
          int ar = wm + f * 16 + lr;
          af[f] = *(short8*)&Als[(ar * 64 + kk * 32 + kg * 8) ^ ((ar & 7) * 8)];
          int br = wn + f * 16 + lr;
          bf[f] = *(short8*)&Bls[(br * 64 + kk * 32 + kg * 8) ^ ((br & 7) * 8)];
        }
#pragma unroll
        for (int fi = 0; fi < 2; ++fi)
#pragma unroll
          for (int fj = 0; fj < 2; ++fj)
            acc[fi][fj] = __builtin_amdgcn_mfma_f32_16x16x32_bf16(
                af[fi], bf[fj], acc[fi][fj], 0, 0, 0);
      }
    }
  }
  int rg = lane >> 4;
#pragma unroll
  for (int fi = 0; fi < 2; ++fi)
#pragma unroll
    for (int fj = 0; fj < 2; ++fj)
#pragma unroll
      for (int r = 0; r < 4; ++r) {
        int gm = m0 + wm + fi * 16 + rg * 4 + r;
        int gn = n0 + wn + fj * 16 + lr;
        float v = acc[fi][fj][r];
        if (sens) {
          if (gn < 1024)      qb[(long)gm * 1024 + gn] = v + bq[gn];
          else if (gn < 1088) ikb[(long)gm * 64 + gn - 1024] = v + bik[gn - 1024];
          else if (gn < 1104) wb[(long)gm * 16 + gn - 1088] = v + biw[gn - 1088];
        } else {
          if (gn < 256) kb[(long)gm * 256 + gn] = v + bk[gn];
          else          vb[(long)gm * 256 + gn - 256] = v + bv[gn - 256];
        }
      }
}

// ---- Wo bf16 GEMM: BM=64, BN=64, grid (16, 32) = 512 blocks ----------------
__global__ __launch_bounds__(256, 8) void gemm_wo(
    const short* __restrict__ A, const short* __restrict__ Bm,
    float* __restrict__ out) {
  __shared__ short Als[64 * 64] __attribute__((aligned(16)));
  __shared__ short Bls[64 * 64] __attribute__((aligned(16)));
  int tid = threadIdx.x;
  int lane = tid & 63, wid = tid >> 6;
  int m0 = blockIdx.y * 64, n0 = blockIdx.x * 64;
  int wm = (wid >> 1) * 32, wn = (wid & 1) * 32;
  int lr = lane & 15, kg = lane >> 4;
  int arow = tid >> 2, aseg4 = tid & 3;
  int abase = arow * 64 + aseg4 * 16;
  int aswz = (arow & 7) * 8;
  const short* aseg = A + (long)(m0 + arow) * 1024 + aseg4 * 16;
  const short* bseg = Bm + (long)(n0 + arow) * 1024 + aseg4 * 16;
  f32x4 acc[2][2] = {};
  short8 a0, a1, b0, b1;
  a0 = *(const short8*)(aseg);
  a1 = *(const short8*)(aseg + 8);
  b0 = *(const short8*)(bseg);
  b1 = *(const short8*)(bseg + 8);
  for (int t = 0; t < 16; ++t) {
    __syncthreads();
    *(short8*)&Als[abase ^ aswz] = a0;
    *(short8*)&Als[(abase + 8) ^ aswz] = a1;
    *(short8*)&Bls[abase ^ aswz] = b0;
    *(short8*)&Bls[(abase + 8) ^ aswz] = b1;
    __syncthreads();
    if (t + 1 < 16) {
      const short* an = aseg + (t + 1) * 64;
      const short* bn = bseg + (t + 1) * 64;
      a0 = *(const short8*)(an);
      a1 = *(const short8*)(an + 8);
      b0 = *(const short8*)(bn);
      b1 = *(const short8*)(bn + 8);
    }
#pragma unroll
    for (int kk = 0; kk < 2; ++kk) {
      short8 af[2], bf[2];
#pragma unroll
      for (int f = 0; f < 2; ++f) {
        int ar = wm + f * 16 + lr;
        af[f] = *(short8*)&Als[(ar * 64 + kk * 32 + kg * 8) ^ ((ar & 7) * 8)];
        int br = wn + f * 16 + lr;
        bf[f] = *(short8*)&Bls[(br * 64 + kk * 32 + kg * 8) ^ ((br & 7) * 8)];
      }
#pragma unroll
      for (int fi = 0; fi < 2; ++fi)
#pragma unroll
        for (int fj = 0; fj < 2; ++fj)
          acc[fi][fj] = __builtin_amdgcn_mfma_f32_16x16x32_bf16(
              af[fi], bf[fj], acc[fi][fj], 0, 0, 0);
    }
  }
  int rg = lane >> 4;
#pragma unroll
  for (int fi = 0; fi < 2; ++fi)
#pragma unroll
    for (int fj = 0; fj < 2; ++fj)
#pragma unroll
      for (int r = 0; r < 4; ++r) {
        int gm = m0 + wm + fi * 16 + rg * 4 + r;
        int gn = n0 + wn + fj * 16 + lr;
        out[(long)gm * 1024 + gn] = acc[fi][fj][r];
      }
}

// ---- RoPE + fused 3-way splits (q,ik) + bf16 K copy ------------------------
__global__ void rope_kernel(float* __restrict__ q, float* __restrict__ k,
                            float* __restrict__ ik, short* __restrict__ k_bf,
                            short* __restrict__ qh, short* __restrict__ qm,
                            short* __restrict__ ql, short* __restrict__ ikh,
                            short* __restrict__ ikm, short* __restrict__ ikl,
                            int big,
                            const float* __restrict__ cosb,
                            const float* __restrict__ sinb) {
  int gid = blockIdx.x * 256 + threadIdx.x;
  const int NV = SEQ * (NH + NKV + 1);
  if (gid >= NV * 32) return;
  int p = gid & 31;
  int vec = gid >> 5;
  int s;
  if (vec < SEQ * NH) {                     // q branch
    s = vec / NH; int h = vec % NH;
    long off = (long)s * 1024 + h * 64;
    float c = cosb[s * 64 + p], sn = sinb[s * 64 + p];
    float x1 = q[off + p], x2 = q[off + p + 32];
    float y1 = x1 * c - x2 * sn;
    float y2 = x2 * c + x1 * sn;
    q[off + p] = y1;
    q[off + p + 32] = y2;
    if (big) {                              // exact 3-way split (== conv_split3)
      short h1, m1, l1, h2, m2, l2;
      split3(y1, h1, m1, l1);
      split3(y2, h2, m2, l2);
      qh[off + p] = h1; qm[off + p] = m1; ql[off + p] = l1;
      qh[off + p + 32] = h2; qm[off + p + 32] = m2; ql[off + p + 32] = l2;
    }
  } else if (vec < SEQ * (NH + NKV)) {      // k branch (+ bf16 copy)
    int t = vec - SEQ * NH;
    s = t / NKV; int kh = t % NKV;
    long off = (long)s * 256 + kh * 64;
    float c = cosb[s * 64 + p], sn = sinb[s * 64 + p];
    float x1 = k[off + p], x2 = k[off + p + 32];
    float y1 = x1 * c - x2 * sn;
    float y2 = x2 * c + x1 * sn;
    k[off + p] = y1;
    k[off + p + 32] = y2;
    k_bf[off + p] = f2bf_bits(y1);
    k_bf[off + p + 32] = f2bf_bits(y2);
  } else {                                  // ik branch (+ splits)
    s = vec - SEQ * (NH + NKV);
    long off = (long)s * 64;
    float c = cosb[s * 64 + p], sn = sinb[s * 64 + p];
    float x1 = ik[off + p], x2 = ik[off + p + 32];
    float y1 = x1 * c - x2 * sn;
    float y2 = x2 * c + x1 * sn;
    ik[off + p] = y1;
    ik[off + p + 32] = y2;
    if (big) {
      short h1, m1, l1, h2, m2, l2;
      split3(y1, h1, m1, l1);
      split3(y2, h2, m2, l2);
      ikh[off + p] = h1; ikm[off + p] = m1; ikl[off + p] = l1;
      ikh[off + p + 32] = h2; ikm[off + p + 32] = m2; ikl[off + p + 32] = l2;
    }
  }
}

// ---- MFMA indexer scores, EXACT 3-way split (6 product terms) --------------
__global__ __launch_bounds__(256) void idx_mfma6(
    const short* __restrict__ q_h, const short* __restrict__ q_m,
    const short* __restrict__ q_l, const short* __restrict__ ik_h,
    const short* __restrict__ ik_m, const short* __restrict__ ik_l,
    const float* __restrict__ wb, float* __restrict__ sc) {
  int b = blockIdx.x;                         // 0..527 triangular
  int tq = (int)((sqrtf(8.f * b + 1.f) - 1.f) * 0.5f);
  while ((tq * (tq + 1)) / 2 > b) --tq;
  while (((tq + 1) * (tq + 2)) / 2 <= b) ++tq;
  int tk = b - (tq * (tq + 1)) / 2;
  int q0 = tq * 64, k0 = tk * 64;

  __shared__ short QH[64 * 64] __attribute__((aligned(16)));
  __shared__ short QM[64 * 64] __attribute__((aligned(16)));
  __shared__ short QL[64 * 64] __attribute__((aligned(16)));
  __shared__ short IH[64 * 64] __attribute__((aligned(16)));
  __shared__ short IM[64 * 64] __attribute__((aligned(16)));
  __shared__ short IL[64 * 64] __attribute__((aligned(16)));
  __shared__ float wls[64][17];

  int tid = threadIdx.x;
  int lane = tid & 63, wid = tid >> 6;
  int wm = (wid >> 1) * 32, wn = (wid & 1) * 32;
  int lr = lane & 15, kg = lane >> 4;
  int sr = tid >> 2, seg = tid & 3;
  int sbase = sr * 64 + seg * 16;
  int sswz = (sr & 7) * 8;

  {  // stage ik tiles (once) + w tile
    const short* g0 = ik_h + (long)(k0 + sr) * 64 + seg * 16;
    const short* g1 = ik_m + (long)(k0 + sr) * 64 + seg * 16;
    const short* g2 = ik_l + (long)(k0 + sr) * 64 + seg * 16;
#pragma unroll
    for (int c = 0; c < 2; ++c) {
      *(short8*)&IH[(sbase + c * 8) ^ sswz] = *(const short8*)(g0 + c * 8);
      *(short8*)&IM[(sbase + c * 8) ^ sswz] = *(const short8*)(g1 + c * 8);
      *(short8*)&IL[(sbase + c * 8) ^ sswz] = *(const short8*)(g2 + c * 8);
    }
    int wlc = tid & 15, wlr = tid >> 4;
#pragma unroll
    for (int i = 0; i < 4; ++i)
      wls[wlr + 16 * i][wlc] = wb[(long)(q0 + wlr + 16 * i) * 16 + wlc] * 0.25f;
  }
  __syncthreads();
  short8 bh[2][2], bm_[2][2], bl_[2][2];
#pragma unroll
  for (int fj = 0; fj < 2; ++fj)
#pragma unroll
    for (int ks = 0; ks < 2; ++ks) {
      int br = wn + fj * 16 + lr;
      int idx = (br * 64 + ks * 32 + kg * 8) ^ ((br & 7) * 8);
      bh[fj][ks] = *(short8*)&IH[idx];
      bm_[fj][ks] = *(short8*)&IM[idx];
      bl_[fj][ks] = *(short8*)&IL[idx];
    }

  int rg = lane >> 4;
  f32x4 acc[2][2] = {};
  for (int h = 0; h < NH; ++h) {
    __syncthreads();
    {
      const short* g0 = q_h + (long)(q0 + sr) * 1024 + h * 64 + seg * 16;
      const short* g1 = q_m + (long)(q0 + sr) * 1024 + h * 64 + seg * 16;
      const short* g2 = q_l + (long)(q0 + sr) * 1024 + h * 64 + seg * 16;
#pragma unroll
      for (int c = 0; c < 2; ++c) {
        *(short8*)&QH[(sbase + c * 8) ^ sswz] = *(const short8*)(g0 + c * 8);
        *(short8*)&QM[(sbase + c * 8) ^ sswz] = *(const short8*)(g1 + c * 8);
        *(short8*)&QL[(sbase + c * 8) ^ sswz] = *(const short8*)(g2 + c * 8);
      }
    }
    __syncthreads();
    f32x4 dot[2][2] = {};
#pragma unroll
    for (int ks = 0; ks < 2; ++ks) {
      short8 ah[2], am[2], al[2];
#pragma unroll
      for (int fi = 0; fi < 2; ++fi) {
        int ar = wm + fi * 16 + lr;
        int idx = (ar * 64 + ks * 32 + kg * 8) ^ ((ar & 7) * 8);
        ah[fi] = *(short8*)&QH[idx];
        am[fi] = *(short8*)&QM[idx];
        al[fi] = *(short8*)&QL[idx];
      }
#pragma unroll
      for (int fi = 0; fi < 2; ++fi)
#pragma unroll
        for (int fj = 0; fj < 2; ++fj) {
          dot[fi][fj] = __builtin_amdgcn_mfma_f32_16x16x32_bf16(
              ah[fi], bh[fj][ks], dot[fi][fj], 0, 0, 0);      // hh
          dot[fi][fj] = __builtin_amdgcn_mfma_f32_16x16x32_bf16(
              ah[fi], bm_[fj][ks], dot[fi][fj], 0, 0, 0);     // hm
          dot[fi][fj] = __builtin_amdgcn_mfma_f32_16x16x32_bf16(
              am[fi], bh[fj][ks], dot[fi][fj], 0, 0, 0);      // mh
          dot[fi][fj] = __builtin_amdgcn_mfma_f32_16x16x32_bf16(
              ah[fi], bl_[fj][ks], dot[fi][fj], 0, 0, 0);     // hl
          dot[fi][fj] = __builtin_amdgcn_mfma_f32_16x16x32_bf16(
              am[fi], bm_[fj][ks], dot[fi][fj], 0, 0, 0);     // mm
          dot[fi][fj] = __builtin_amdgcn_mfma_f32_16x16x32_bf16(
              al[fi], bh[fj][ks], dot[fi][fj], 0, 0, 0);      // lh
        }
    }
#pragma unroll
    for (int fi = 0; fi < 2; ++fi) {
      float wv[4];
#pragma unroll
      for (int r = 0; r < 4; ++r) wv[r] = wls[wm + fi * 16 + rg * 4 + r][h];
#pragma unroll
      for (int fj = 0; fj < 2; ++fj)
#pragma unroll
        for (int r = 0; r < 4; ++r)
          acc[fi][fj][r] += fmaxf(dot[fi][fj][r], 0.f) * wv[r];
    }
  }
#pragma unroll
  for (int fi = 0; fi < 2; ++fi)
#pragma unroll
    for (int fj = 0; fj < 2; ++fj)
#pragma unroll
      for (int r = 0; r < 4; ++r) {
        int q = q0 + wm + fi * 16 + rg * 4 + r;
        int k = k0 + wn + fj * 16 + lr;
        if (k <= q) sc[(long)q * (q + 1) / 2 + k] = acc[fi][fj][r];
      }
}

// ---- fallback VALU indexer (if ws too small for splits) --------------------
__global__ __launch_bounds__(256) void idx_scores(
    const float* __restrict__ qb, const float* __restrict__ ikb,
    const float* __restrict__ wb, float* __restrict__ sc) {
  int b = blockIdx.x;
  int tq = (int)((sqrtf(8.f * b + 1.f) - 1.f) * 0.5f);
  while ((tq * (tq + 1)) / 2 > b) --tq;
  while (((tq + 1) * (tq + 2)) / 2 <= b) ++tq;
  int tk = b - (tq * (tq + 1)) / 2;
  int q0 = tq * 64, k0 = tk * 64;
  __shared__ float As0[64][68];
  __shared__ float As1[64][68];
  __shared__ float Bs[64][68];
  __shared__ float wls[64][17];
  int tid = threadIdx.x;
  int lc = tid & 15, lr = tid >> 4;
  int tx = lc, ty = lr;
#pragma unroll
  for (int c = 0; c < 4; ++c) {
    int d = c * 16 + lc;
#pragma unroll
    for (int i = 0; i < 4; ++i)
      Bs[d][lr + 16 * i] = ikb[(long)(k0 + lr + 16 * i) * 64 + d];
  }
#pragma unroll
  for (int i = 0; i < 4; ++i)
    wls[lr + 16 * i][lc] = wb[(long)(q0 + lr + 16 * i) * 16 + lc] * 0.25f;
  float pf0[16], pf1[16];
#pragma unroll
  for (int c = 0; c < 4; ++c)
#pragma unroll
    for (int i = 0; i < 4; ++i) {
      long base = (long)(q0 + lr + 16 * i) * 1024 + c * 16 + lc;
      pf0[c * 4 + i] = qb[base];
      pf1[c * 4 + i] = qb[base + 64];
    }
  float acc[4][4] = {};
  for (int hp = 0; hp < 8; ++hp) {
    __syncthreads();
#pragma unroll
    for (int c = 0; c < 4; ++c)
#pragma unroll
      for (int i = 0; i < 4; ++i) {
        As0[c * 16 + lc][lr + 16 * i] = pf0[c * 4 + i];
        As1[c * 16 + lc][lr + 16 * i] = pf1[c * 4 + i];
      }
    if (hp < 7) {
#pragma unroll
      for (int c = 0; c < 4; ++c)
#pragma unroll
        for (int i = 0; i < 4; ++i) {
          long base =
              (long)(q0 + lr + 16 * i) * 1024 + (2 * hp + 2) * 64 + c * 16 + lc;
          pf0[c * 4 + i] = qb[base];
          pf1[c * 4 + i] = qb[base + 64];
        }
    }
    __syncthreads();
    float wv0[4], wv1[4];
#pragma unroll
    for (int i = 0; i < 4; ++i) {
      wv0[i] = wls[ty * 4 + i][2 * hp];
      wv1[i] = wls[ty * 4 + i][2 * hp + 1];
    }
    float dot0[4][4] = {}, dot1[4][4] = {};
#pragma unroll
    for (int kk = 0; kk < 64; ++kk) {
      float4 a0 = *(const float4*)&As0[kk][ty * 4];
      float4 a1 = *(const float4*)&As1[kk][ty * 4];
      float4 b4 = *(const float4*)&Bs[kk][tx * 4];
      float av0[4] = {a0.x, a0.y, a0.z, a0.w};
      float av1[4] = {a1.x, a1.y, a1.z, a1.w};
      float bv[4] = {b4.x, b4.y, b4.z, b4.w};
#pragma unroll
      for (int i = 0; i < 4; ++i)
#pragma unroll
        for (int j = 0; j < 4; ++j) {
          dot0[i][j] += av0[i] * bv[j];
          dot1[i][j] += av1[i] * bv[j];
        }
    }
#pragma unroll
    for (int i = 0; i < 4; ++i)
#pragma unroll
      for (int j = 0; j < 4; ++j) {
        acc[i][j] += fmaxf(dot0[i][j], 0.f) * wv0[i];
        acc[i][j] += fmaxf(dot1[i][j], 0.f) * wv1[i];
      }
  }
#pragma unroll
  for (int i = 0; i < 4; ++i) {
    int q = q0 + ty * 4 + i;
    long base = (long)q * (q + 1) / 2;
#pragma unroll
    for (int j = 0; j < 4; ++j) {
      int k = k0 + tx * 4 + j;
      if (k <= q) sc[base + k] = acc[i][j];
    }
  }
}

// ---- exact top-128 per row, one wave per row -------------------------------
__device__ inline unsigned fkey(float f) {
  unsigned u = __float_as_uint(f);
  return (u & 0x80000000u) ? ~u : (u | 0x80000000u);
}

__global__ __launch_bounds__(64) void topk_rows(
    const float* __restrict__ sc, int* __restrict__ tidx,
    int* __restrict__ tcnt) {
  int qi = blockIdx.x;
  int lane = threadIdx.x;
  if (qi < TOPK) {
    for (int i = lane; i <= qi; i += 64) tidx[(long)qi * TOPK + i] = i;
    if (lane == 0) tcnt[qi] = qi + 1;
    return;
  }
  const float* row = sc + (long)qi * (qi + 1) / 2;
  unsigned keys[32];
#pragma unroll
  for (int i = 0; i < 32; ++i) {
    int k = lane + 64 * i;
    keys[i] = (k <= qi) ? fkey(row[k] + 0.f) : 0u;
  }
  unsigned lo = 0u, hi = 0xFFFFFFFEu;
  while (lo < hi) {
    unsigned mid = lo + ((hi - lo + 1) >> 1);
    int cnt = 0;
#pragma unroll
    for (int i = 0; i < 32; ++i) cnt += (keys[i] >= mid) ? 1 : 0;
    for (int off = 32; off; off >>= 1) cnt += __shfl_xor(cnt, off);
    if (cnt >= TOPK) lo = mid; else hi = mid - 1;
  }
  unsigned T = lo;
  __shared__ int c1;
  if (lane == 0) c1 = 0;
  __syncthreads();
#pragma unroll
  for (int i = 0; i < 32; ++i) {
    if (keys[i] > T) {
      int pos = atomicAdd(&c1, 1);
      tidx[(long)qi * TOPK + pos] = lane + 64 * i;
    }
  }
  __syncthreads();
  int c = c1;
  for (int i = 0; i < 32 && c < TOPK; ++i) {
    unsigned long long m = __ballot(keys[i] == T);
    while (m && c < TOPK) {
      int l = __ffsll(m) - 1;
      m &= m - 1;
      if (lane == 0) tidx[(long)qi * TOPK + c] = 64 * i + l;
      ++c;
    }
  }
  if (lane == 0) tcnt[qi] = TOPK;
}

// ---- sparse attention: block (q, kvh); 4 waves; K staged as bf16 in LDS ----
__global__ __launch_bounds__(256) void sparse_attn(
    const float* __restrict__ qb, const short* __restrict__ kb_bf,
    const float* __restrict__ vb, const int* __restrict__ tidx,
    const int* __restrict__ tcnt, short* __restrict__ attn) {
  int kvh = blockIdx.x;
  int qi  = blockIdx.y;
  int tid = threadIdx.x, lane = tid & 63, w = tid >> 6;
  int h = kvh * 4 + w;
  int cnt = tcnt[qi];
  __shared__ int   idxs[128];
  __shared__ short Ks[128][68] __attribute__((aligned(16)));
  __shared__ float qs[4][64];
  __shared__ float ps[4][128];
  if (tid < 128) idxs[tid] = (tid < cnt) ? tidx[(long)qi * TOPK + tid] : 0;
  qs[w][lane] = qb[(long)qi * 1024 + h * 64 + lane];
  __syncthreads();
  {
    int j0 = tid >> 2, qf = tid & 3;     // 4 threads per K row (coalesced)
#pragma unroll
    for (int pass = 0; pass < 2; ++pass) {
      int j = j0 + pass * 64;
      if (j < cnt) {
        int ki = idxs[j];
        const short* kr = kb_bf + (long)ki * 256 + kvh * 64 + qf * 16;
        short8 k0 = *(const short8*)(kr);
        short8 k1 = *(const short8*)(kr + 8);
        *(short4*)&Ks[j][qf * 16 + 0]  = *(short4*)&k0;
        *(short4*)&Ks[j][qf * 16 + 4]  = *((short4*)&k0 + 1);
        *(short4*)&Ks[j][qf * 16 + 8]  = *(short4*)&k1;
        *(short4*)&Ks[j][qf * 16 + 12] = *((short4*)&k1 + 1);
      }
    }
  }
  __syncthreads();
  float4 qreg[16];
#pragma unroll
  for (int c = 0; c < 16; ++c) qreg[c] = *(const float4*)&qs[w][c * 4];
  float l0 = -INFINITY, l1 = -INFINITY;
#pragma unroll
  for (int slot = 0; slot < 2; ++slot) {
    int j = lane + slot * 64;
    if (j < cnt) {
      float d = 0.f;
#pragma unroll
      for (int c = 0; c < 16; ++c) {
        short4 kk4 = *(const short4*)&Ks[j][c * 4];
        d += qreg[c].x * bf2f(kk4.x);
        d += qreg[c].y * bf2f(kk4.y);
        d += qreg[c].z * bf2f(kk4.z);
        d += qreg[c].w * bf2f(kk4.w);
      }
      float l = d * 0.125f;
      if (slot == 0) l0 = l; else l1 = l;
    }
  }
  float m = fmaxf(l0, l1);
  for (int off = 32; off; off >>= 1) m = fmaxf(m, __shfl_xor(m, off));
  float p0 = expf(l0 - m), p1 = expf(l1 - m);
  float ssum = p0 + p1;
  for (int off = 32; off; off >>= 1) ssum += __shfl_xor(ssum, off);
  ps[w][lane] = p0;
  ps[w][lane + 64] = p1;
  __syncthreads();
  int sub = lane >> 4, quad = lane & 15;
  float4 o4 = {0.f, 0.f, 0.f, 0.f};
#pragma unroll 4
  for (int j = sub; j < cnt; j += 4) {
    int ki = idxs[j];
    float p = ps[w][j];
    float4 vv = *(const float4*)(vb + (long)ki * 256 + kvh * 64 + quad * 4);
    o4.x += p * vv.x; o4.y += p * vv.y;
    o4.z += p * vv.z; o4.w += p * vv.w;
  }
#pragma unroll
  for (int off = 16; off <= 32; off <<= 1) {
    o4.x += __shfl_xor(o4.x, off);
    o4.y += __shfl_xor(o4.y, off);
    o4.z += __shfl_xor(o4.z, off);
    o4.w += __shfl_xor(o4.w, off);
  }
  if (sub == 0) {
    float inv = 1.f / ssum;
    short4 ov;
    ov.x = f2bf_bits(o4.x * inv); ov.y = f2bf_bits(o4.y * inv);
    ov.z = f2bf_bits(o4.z * inv); ov.w = f2bf_bits(o4.w * inv);
    *(short4*)&attn[(long)qi * 1024 + h * 64 + quad * 4] = ov;
  }
}

// ---- f32 -> bf16 (hi only), standalone for Wo -----------------------------
__global__ __launch_bounds__(256) void conv_hi(
    const float* __restrict__ src, short* __restrict__ dst, int n4) {
  int i = blockIdx.x * 256 + threadIdx.x;
  if (i >= n4) return;
  float4 v = *(const float4*)(src + (long)i * 4);
  short4 hv;
  hv.x = f2bf_bits(v.x); hv.y = f2bf_bits(v.y);
  hv.z = f2bf_bits(v.z); hv.w = f2bf_bits(v.w);
  *(short4*)&dst[(long)i * 4] = hv;
}

// ---------------------------------------------------------------------------
extern "C" void kernel_launch(void* const* d_in, const int* in_sizes, int n_in,
                              void* d_out, int out_size, void* d_ws,
                              size_t ws_size, hipStream_t stream) {
  const float* hs   = (const float*)d_in[0];
  const float* cosb = (const float*)d_in[1];
  const float* sinb = (const float*)d_in[2];
  const float* Wq   = (const float*)d_in[3];
  const float* bq   = (const float*)d_in[4];
  const float* Wk   = (const float*)d_in[5];
  const float* bk   = (const float*)d_in[6];
  const float* Wv   = (const float*)d_in[7];
  const float* bv   = (const float*)d_in[8];
  const float* Wo   = (const float*)d_in[9];
  const float* Wik  = (const float*)d_in[10];
  const float* bik  = (const float*)d_in[11];
  const float* Wiw  = (const float*)d_in[12];
  const float* biw  = (const float*)d_in[13];
  float* out = (float*)d_out;

  float* ws = (float*)d_ws;
  float* qb   = ws;  ws += (long)SEQ * 1024;
  float* kb   = ws;  ws += (long)SEQ * 256;
  float* vb   = ws;  ws += (long)SEQ * 256;
  float* ikb  = ws;  ws += (long)SEQ * 64;
  float* wb   = ws;  ws += (long)SEQ * 16;
  int* tidx   = (int*)ws;  ws += (long)SEQ * TOPK;
  int* tcnt   = (int*)ws;  ws += SEQ;
  short* kb_bf = (short*)ws; ws += (long)SEQ * 128;   // S x 256 bf16 = 1 MB
  float* R1   = ws;  ws += (long)SEQ * (SEQ + 1) / 2;
  float* R2   = ws;  ws += (long)1104 * 1024;
  float* R3   = ws;  ws += 3L * SEQ * 512;         // q_h/m/l: 3 x 2M shorts
  size_t need_big = (size_t)(ws - (float*)d_ws) * 4;   // ~40.8 MB
  int big = ws_size >= need_big;

  short* A_cat   = (short*)R1;          // 8 MB (dead before scores)
  float* scores  = R1;
  short* Wh      = (short*)R2;
  short* Wl      = Wh + (long)1104 * 1024;
  short* attn_bf = (short*)R2;          // Wh/Wl dead by then
  short* Wkv_bf  = (short*)tidx;        // dead before tidx written
  short* Wo_bf   = (short*)qb;          // qb dead after sparse_attn
  short* q_h     = (short*)R3;          // 4 MB each
  short* q_m     = q_h + (long)SEQ * 1024;
  short* q_l     = q_m + (long)SEQ * 1024;
  short* ik_h    = (short*)tidx;        // 3 x 256KB <= 1MB
  short* ik_m    = ik_h + (long)SEQ * 64;
  short* ik_l    = ik_m + (long)SEQ * 64;

  dim3 blk(256);
  conv_all<<<3664, blk, 0, stream>>>(hs, Wq, Wik, Wiw, Wk, Wv, A_cat, Wh, Wl,
                                     Wkv_bf);
  gemm_all<<<dim3(26, 32), blk, 0, stream>>>(A_cat, Wh, Wl, Wkv_bf, bq, bik,
                                             biw, bk, bv, qb, ikb, wb, kb, vb);

  int nrope = SEQ * (NH + NKV + 1) * 32;
  rope_kernel<<<(nrope + 255) / 256, blk, 0, stream>>>(
      qb, kb, ikb, kb_bf, q_h, q_m, q_l, ik_h, ik_m, ik_l, big, cosb, sinb);

  if (big) {
    idx_mfma6<<<528, blk, 0, stream>>>(q_h, q_m, q_l, ik_h, ik_m, ik_l, wb,
                                       scores);
  } else {
    idx_scores<<<528, blk, 0, stream>>>(qb, ikb, wb, scores);
  }
  topk_rows<<<SEQ, dim3(64), 0, stream>>>(scores, tidx, tcnt);

  sparse_attn<<<dim3(NKV, SEQ), blk, 0, stream>>>(qb, kb_bf, vb, tidx, tcnt,
                                                  attn_bf);

  conv_hi<<<1024, blk, 0, stream>>>(Wo, Wo_bf, 1024 * 256);
  gemm_wo<<<dim3(16, 32), blk, 0, stream>>>(attn_bf, Wo_bf, out);
}

// Round 27
// 190.445 us; speedup vs baseline: 1.2104x; 1.2104x over previous
//
#include <hip/hip_runtime.h>
#include <hip/hip_bf16.h>
#include <math.h>

#define SEQ   2048
#define HDIM  1024
#define NH    16
#define NKV   4
#define DHEAD 64
#define TOPK  128

typedef __attribute__((ext_vector_type(8))) short short8;
typedef __attribute__((ext_vector_type(4))) float f32x4;

__device__ inline short f2bf_bits(float x) {          // RTN-even f32 -> bf16
  unsigned u = __float_as_uint(x);
  unsigned r = (u + 0x7FFFu + ((u >> 16) & 1u)) >> 16;
  return (short)r;
}
__device__ inline float bf2f(short s) {
  return __uint_as_float(((unsigned)(unsigned short)s) << 16);
}
__device__ inline void split3(float x, short& h, short& m, short& l) {
  h = f2bf_bits(x);
  float r1 = x - bf2f(h);
  m = f2bf_bits(r1);
  l = f2bf_bits(r1 - bf2f(m));
}

// ---- fused conversions: one dispatch, segmented grid -----------------------
__global__ __launch_bounds__(256) void conv_all(
    const float* __restrict__ hs, const float* __restrict__ Wq,
    const float* __restrict__ Wik, const float* __restrict__ Wiw,
    const float* __restrict__ Wk, const float* __restrict__ Wv,
    short* __restrict__ A_cat, short* __restrict__ Wh, short* __restrict__ Wl,
    short* __restrict__ Wkv) {
  int bb = blockIdx.x;
  int t = threadIdx.x;
  if (bb < 2048) {                          // hs split -> concat rows
    int i = bb * 256 + t;
    float4 v = *(const float4*)(hs + (long)i * 4);
    int r = i >> 8, c = (i & 255) * 4;
    short4 hv, lv;
    short h0 = f2bf_bits(v.x), h1 = f2bf_bits(v.y);
    short h2 = f2bf_bits(v.z), h3 = f2bf_bits(v.w);
    hv.x = h0; hv.y = h1; hv.z = h2; hv.w = h3;
    lv.x = f2bf_bits(v.x - bf2f(h0)); lv.y = f2bf_bits(v.y - bf2f(h1));
    lv.z = f2bf_bits(v.z - bf2f(h2)); lv.w = f2bf_bits(v.w - bf2f(h3));
    *(short4*)&A_cat[(long)r * 2048 + c] = hv;
    *(short4*)&A_cat[(long)r * 2048 + 1024 + c] = lv;
    return;
  }
  const float* src; short *dhi, *dlo; int i;
  if (bb < 3072)      { src = Wq;  dhi = Wh; dlo = Wl;
                        i = (bb - 2048) * 256 + t; }
  else if (bb < 3136) { src = Wik; dhi = Wh + (long)1024 * 1024;
                        dlo = Wl + (long)1024 * 1024;
                        i = (bb - 3072) * 256 + t; }
  else if (bb < 3152) { src = Wiw; dhi = Wh + (long)1088 * 1024;
                        dlo = Wl + (long)1088 * 1024;
                        i = (bb - 3136) * 256 + t; }
  else if (bb < 3408) { src = Wk;  dhi = Wkv; dlo = nullptr;
                        i = (bb - 3152) * 256 + t; }
  else                { src = Wv;  dhi = Wkv + (long)256 * 1024; dlo = nullptr;
                        i = (bb - 3408) * 256 + t; }
  float4 v = *(const float4*)(src + (long)i * 4);
  short4 hv;
  short h0 = f2bf_bits(v.x), h1 = f2bf_bits(v.y);
  short h2 = f2bf_bits(v.z), h3 = f2bf_bits(v.w);
  hv.x = h0; hv.y = h1; hv.z = h2; hv.w = h3;
  *(short4*)&dhi[(long)i * 4] = hv;
  if (dlo) {
    short4 lv;
    lv.x = f2bf_bits(v.x - bf2f(h0)); lv.y = f2bf_bits(v.y - bf2f(h1));
    lv.z = f2bf_bits(v.z - bf2f(h2)); lv.w = f2bf_bits(v.w - bf2f(h3));
    *(short4*)&dlo[(long)i * 4] = lv;
  }
}

// ---- fused projection GEMM: BM=64, BN=64, grid (26, 32) = 832 blocks -------
__global__ __launch_bounds__(256) void gemm_all(
    const short* __restrict__ A_cat, const short* __restrict__ Wh,
    const short* __restrict__ Wl, const short* __restrict__ Wkv,
    const float* __restrict__ bq, const float* __restrict__ bik,
    const float* __restrict__ biw, const float* __restrict__ bk,
    const float* __restrict__ bv, float* __restrict__ qb,
    float* __restrict__ ikb, float* __restrict__ wb, float* __restrict__ kb,
    float* __restrict__ vb) {
  __shared__ short Als[64 * 64] __attribute__((aligned(16)));
  __shared__ short Bls[64 * 64] __attribute__((aligned(16)));
  int bx = blockIdx.x;
  bool sens = bx < 18;
  int n0 = (sens ? bx : bx - 18) * 64;
  int m0 = blockIdx.y * 64;
  int Nrows = sens ? 1104 : 512;
  int nterm = sens ? 3 : 1;
  int tid = threadIdx.x;
  int lane = tid & 63, wid = tid >> 6;
  int wm = (wid >> 1) * 32, wn = (wid & 1) * 32;   // wave: 32x32 output
  int lr = lane & 15, kg = lane >> 4;
  int arow = tid >> 2, aseg4 = tid & 3;
  int abase = arow * 64 + aseg4 * 16;
  int aswz = (arow & 7) * 8;
  bool bok = (n0 + arow) < Nrows;

  f32x4 acc[2][2] = {};
  for (int term = 0; term < nterm; ++term) {
    const short* Ab = A_cat + (term == 1 ? 1024 : 0);
    const short* Bb = sens ? (term == 2 ? Wl : Wh) : Wkv;
    const short* aseg = Ab + (long)(m0 + arow) * 2048 + aseg4 * 16;
    const short* bseg = Bb + (long)(n0 + arow) * 1024 + aseg4 * 16;
    short8 a0, a1, b0, b1;
    a0 = *(const short8*)(aseg);
    a1 = *(const short8*)(aseg + 8);
    b0 = bok ? *(const short8*)(bseg) : short8{};
    b1 = bok ? *(const short8*)(bseg + 8) : short8{};
    for (int t = 0; t < 16; ++t) {
      __syncthreads();
      *(short8*)&Als[abase ^ aswz] = a0;
      *(short8*)&Als[(abase + 8) ^ aswz] = a1;
      *(short8*)&Bls[abase ^ aswz] = b0;
      *(short8*)&Bls[(abase + 8) ^ aswz] = b1;
      __syncthreads();
      if (t + 1 < 16) {
        const short* an = aseg + (t + 1) * 64;
        const short* bn = bseg + (t + 1) * 64;
        a0 = *(const short8*)(an);
        a1 = *(const short8*)(an + 8);
        b0 = bok ? *(const short8*)(bn) : short8{};
        b1 = bok ? *(const short8*)(bn + 8) : short8{};
      }
#pragma unroll
      for (int kk = 0; kk < 2; ++kk) {
        short8 af[2], bf[2];
#pragma unroll
        for (int f = 0; f < 2; ++f) {
          int ar = wm + f * 16 + lr;
          af[f] = *(short8*)&Als[(ar * 64 + kk * 32 + kg * 8) ^ ((ar & 7) * 8)];
          int br = wn + f * 16 + lr;
          bf[f] = *(short8*)&Bls[(br * 64 + kk * 32 + kg * 8) ^ ((br & 7) * 8)];
        }
#pragma unroll
        for (int fi = 0; fi < 2; ++fi)
#pragma unroll
          for (int fj = 0; fj < 2; ++fj)
            acc[fi][fj] = __builtin_amdgcn_mfma_f32_16x16x32_bf16(
                af[fi], bf[fj], acc[fi][fj], 0, 0, 0);
      }
    }
  }
  int rg = lane >> 4;
#pragma unroll
  for (int fi = 0; fi < 2; ++fi)
#pragma unroll
    for (int fj = 0; fj < 2; ++fj)
#pragma unroll
      for (int r = 0; r < 4; ++r) {
        int gm = m0 + wm + fi * 16 + rg * 4 + r;
        int gn = n0 + wn + fj * 16 + lr;
        float v = acc[fi][fj][r];
        if (sens) {
          if (gn < 1024)      qb[(long)gm * 1024 + gn] = v + bq[gn];
          else if (gn < 1088) ikb[(long)gm * 64 + gn - 1024] = v + bik[gn - 1024];
          else if (gn < 1104) wb[(long)gm * 16 + gn - 1088] = v + biw[gn - 1088];
        } else {
          if (gn < 256) kb[(long)gm * 256 + gn] = v + bk[gn];
          else          vb[(long)gm * 256 + gn - 256] = v + bv[gn - 256];
        }
      }
}

// ---- Wo bf16 GEMM: BM=64, BN=64, grid (16, 32) = 512 blocks ----------------
__global__ __launch_bounds__(256) void gemm_wo(
    const short* __restrict__ A, const short* __restrict__ Bm,
    float* __restrict__ out) {
  __shared__ short Als[64 * 64] __attribute__((aligned(16)));
  __shared__ short Bls[64 * 64] __attribute__((aligned(16)));
  int tid = threadIdx.x;
  int lane = tid & 63, wid = tid >> 6;
  int m0 = blockIdx.y * 64, n0 = blockIdx.x * 64;
  int wm = (wid >> 1) * 32, wn = (wid & 1) * 32;
  int lr = lane & 15, kg = lane >> 4;
  int arow = tid >> 2, aseg4 = tid & 3;
  int abase = arow * 64 + aseg4 * 16;
  int aswz = (arow & 7) * 8;
  const short* aseg = A + (long)(m0 + arow) * 1024 + aseg4 * 16;
  const short* bseg = Bm + (long)(n0 + arow) * 1024 + aseg4 * 16;
  f32x4 acc[2][2] = {};
  short8 a0, a1, b0, b1;
  a0 = *(const short8*)(aseg);
  a1 = *(const short8*)(aseg + 8);
  b0 = *(const short8*)(bseg);
  b1 = *(const short8*)(bseg + 8);
  for (int t = 0; t < 16; ++t) {
    __syncthreads();
    *(short8*)&Als[abase ^ aswz] = a0;
    *(short8*)&Als[(abase + 8) ^ aswz] = a1;
    *(short8*)&Bls[abase ^ aswz] = b0;
    *(short8*)&Bls[(abase + 8) ^ aswz] = b1;
    __syncthreads();
    if (t + 1 < 16) {
      const short* an = aseg + (t + 1) * 64;
      const short* bn = bseg + (t + 1) * 64;
      a0 = *(const short8*)(an);
      a1 = *(const short8*)(an + 8);
      b0 = *(const short8*)(bn);
      b1 = *(const short8*)(bn + 8);
    }
#pragma unroll
    for (int kk = 0; kk < 2; ++kk) {
      short8 af[2], bf[2];
#pragma unroll
      for (int f = 0; f < 2; ++f) {
        int ar = wm + f * 16 + lr;
        af[f] = *(short8*)&Als[(ar * 64 + kk * 32 + kg * 8) ^ ((ar & 7) * 8)];
        int br = wn + f * 16 + lr;
        bf[f] = *(short8*)&Bls[(br * 64 + kk * 32 + kg * 8) ^ ((br & 7) * 8)];
      }
#pragma unroll
      for (int fi = 0; fi < 2; ++fi)
#pragma unroll
        for (int fj = 0; fj < 2; ++fj)
          acc[fi][fj] = __builtin_amdgcn_mfma_f32_16x16x32_bf16(
              af[fi], bf[fj], acc[fi][fj], 0, 0, 0);
    }
  }
  int rg = lane >> 4;
#pragma unroll
  for (int fi = 0; fi < 2; ++fi)
#pragma unroll
    for (int fj = 0; fj < 2; ++fj)
#pragma unroll
      for (int r = 0; r < 4; ++r) {
        int gm = m0 + wm + fi * 16 + rg * 4 + r;
        int gn = n0 + wn + fj * 16 + lr;
        out[(long)gm * 1024 + gn] = acc[fi][fj][r];
      }
}

// ---- RoPE + fused 3-way splits (q,ik) + bf16 K copy ------------------------
__global__ void rope_kernel(float* __restrict__ q, float* __restrict__ k,
                            float* __restrict__ ik, short* __restrict__ k_bf,
                            short* __restrict__ qh, short* __restrict__ qm,
                            short* __restrict__ ql, short* __restrict__ ikh,
                            short* __restrict__ ikm, short* __restrict__ ikl,
                            int big,
                            const float* __restrict__ cosb,
                            const float* __restrict__ sinb) {
  int gid = blockIdx.x * 256 + threadIdx.x;
  const int NV = SEQ * (NH + NKV + 1);
  if (gid >= NV * 32) return;
  int p = gid & 31;
  int vec = gid >> 5;
  int s;
  if (vec < SEQ * NH) {                     // q branch
    s = vec / NH; int h = vec % NH;
    long off = (long)s * 1024 + h * 64;
    float c = cosb[s * 64 + p], sn = sinb[s * 64 + p];
    float x1 = q[off + p], x2 = q[off + p + 32];
    float y1 = x1 * c - x2 * sn;
    float y2 = x2 * c + x1 * sn;
    q[off + p] = y1;
    q[off + p + 32] = y2;
    if (big) {                              // exact 3-way split (== conv_split3)
      short h1, m1, l1, h2, m2, l2;
      split3(y1, h1, m1, l1);
      split3(y2, h2, m2, l2);
      qh[off + p] = h1; qm[off + p] = m1; ql[off + p] = l1;
      qh[off + p + 32] = h2; qm[off + p + 32] = m2; ql[off + p + 32] = l2;
    }
  } else if (vec < SEQ * (NH + NKV)) {      // k branch (+ bf16 copy)
    int t = vec - SEQ * NH;
    s = t / NKV; int kh = t % NKV;
    long off = (long)s * 256 + kh * 64;
    float c = cosb[s * 64 + p], sn = sinb[s * 64 + p];
    float x1 = k[off + p], x2 = k[off + p + 32];
    float y1 = x1 * c - x2 * sn;
    float y2 = x2 * c + x1 * sn;
    k[off + p] = y1;
    k[off + p + 32] = y2;
    k_bf[off + p] = f2bf_bits(y1);
    k_bf[off + p + 32] = f2bf_bits(y2);
  } else {                                  // ik branch (+ splits)
    s = vec - SEQ * (NH + NKV);
    long off = (long)s * 64;
    float c = cosb[s * 64 + p], sn = sinb[s * 64 + p];
    float x1 = ik[off + p], x2 = ik[off + p + 32];
    float y1 = x1 * c - x2 * sn;
    float y2 = x2 * c + x1 * sn;
    ik[off + p] = y1;
    ik[off + p + 32] = y2;
    if (big) {
      short h1, m1, l1, h2, m2, l2;
      split3(y1, h1, m1, l1);
      split3(y2, h2, m2, l2);
      ikh[off + p] = h1; ikm[off + p] = m1; ikl[off + p] = l1;
      ikh[off + p + 32] = h2; ikm[off + p + 32] = m2; ikl[off + p + 32] = l2;
    }
  }
}

// ---- MFMA indexer scores, EXACT 3-way split (6 product terms) --------------
__global__ __launch_bounds__(256) void idx_mfma6(
    const short* __restrict__ q_h, const short* __restrict__ q_m,
    const short* __restrict__ q_l, const short* __restrict__ ik_h,
    const short* __restrict__ ik_m, const short* __restrict__ ik_l,
    const float* __restrict__ wb, float* __restrict__ sc) {
  int b = blockIdx.x;                         // 0..527 triangular
  int tq = (int)((sqrtf(8.f * b + 1.f) - 1.f) * 0.5f);
  while ((tq * (tq + 1)) / 2 > b) --tq;
  while (((tq + 1) * (tq + 2)) / 2 <= b) ++tq;
  int tk = b - (tq * (tq + 1)) / 2;
  int q0 = tq * 64, k0 = tk * 64;

  __shared__ short QH[64 * 64] __attribute__((aligned(16)));
  __shared__ short QM[64 * 64] __attribute__((aligned(16)));
  __shared__ short QL[64 * 64] __attribute__((aligned(16)));
  __shared__ short IH[64 * 64] __attribute__((aligned(16)));
  __shared__ short IM[64 * 64] __attribute__((aligned(16)));
  __shared__ short IL[64 * 64] __attribute__((aligned(16)));
  __shared__ float wls[64][17];

  int tid = threadIdx.x;
  int lane = tid & 63, wid = tid >> 6;
  int wm = (wid >> 1) * 32, wn = (wid & 1) * 32;
  int lr = lane & 15, kg = lane >> 4;
  int sr = tid >> 2, seg = tid & 3;
  int sbase = sr * 64 + seg * 16;
  int sswz = (sr & 7) * 8;

  {  // stage ik tiles (once) + w tile
    const short* g0 = ik_h + (long)(k0 + sr) * 64 + seg * 16;
    const short* g1 = ik_m + (long)(k0 + sr) * 64 + seg * 16;
    const short* g2 = ik_l + (long)(k0 + sr) * 64 + seg * 16;
#pragma unroll
    for (int c = 0; c < 2; ++c) {
      *(short8*)&IH[(sbase + c * 8) ^ sswz] = *(const short8*)(g0 + c * 8);
      *(short8*)&IM[(sbase + c * 8) ^ sswz] = *(const short8*)(g1 + c * 8);
      *(short8*)&IL[(sbase + c * 8) ^ sswz] = *(const short8*)(g2 + c * 8);
    }
    int wlc = tid & 15, wlr = tid >> 4;
#pragma unroll
    for (int i = 0; i < 4; ++i)
      wls[wlr + 16 * i][wlc] = wb[(long)(q0 + wlr + 16 * i) * 16 + wlc] * 0.25f;
  }
  __syncthreads();
  short8 bh[2][2], bm_[2][2], bl_[2][2];
#pragma unroll
  for (int fj = 0; fj < 2; ++fj)
#pragma unroll
    for (int ks = 0; ks < 2; ++ks) {
      int br = wn + fj * 16 + lr;
      int idx = (br * 64 + ks * 32 + kg * 8) ^ ((br & 7) * 8);
      bh[fj][ks] = *(short8*)&IH[idx];
      bm_[fj][ks] = *(short8*)&IM[idx];
      bl_[fj][ks] = *(short8*)&IL[idx];
    }

  int rg = lane >> 4;
  f32x4 acc[2][2] = {};
  for (int h = 0; h < NH; ++h) {
    __syncthreads();
    {
      const short* g0 = q_h + (long)(q0 + sr) * 1024 + h * 64 + seg * 16;
      const short* g1 = q_m + (long)(q0 + sr) * 1024 + h * 64 + seg * 16;
      const short* g2 = q_l + (long)(q0 + sr) * 1024 + h * 64 + seg * 16;
#pragma unroll
      for (int c = 0; c < 2; ++c) {
        *(short8*)&QH[(sbase + c * 8) ^ sswz] = *(const short8*)(g0 + c * 8);
        *(short8*)&QM[(sbase + c * 8) ^ sswz] = *(const short8*)(g1 + c * 8);
        *(short8*)&QL[(sbase + c * 8) ^ sswz] = *(const short8*)(g2 + c * 8);
      }
    }
    __syncthreads();
    f32x4 dot[2][2] = {};
#pragma unroll
    for (int ks = 0; ks < 2; ++ks) {
      short8 ah[2], am[2], al[2];
#pragma unroll
      for (int fi = 0; fi < 2; ++fi) {
        int ar = wm + fi * 16 + lr;
        int idx = (ar * 64 + ks * 32 + kg * 8) ^ ((ar & 7) * 8);
        ah[fi] = *(short8*)&QH[idx];
        am[fi] = *(short8*)&QM[idx];
        al[fi] = *(short8*)&QL[idx];
      }
#pragma unroll
      for (int fi = 0; fi < 2; ++fi)
#pragma unroll
        for (int fj = 0; fj < 2; ++fj) {
          dot[fi][fj] = __builtin_amdgcn_mfma_f32_16x16x32_bf16(
              ah[fi], bh[fj][ks], dot[fi][fj], 0, 0, 0);      // hh
          dot[fi][fj] = __builtin_amdgcn_mfma_f32_16x16x32_bf16(
              ah[fi], bm_[fj][ks], dot[fi][fj], 0, 0, 0);     // hm
          dot[fi][fj] = __builtin_amdgcn_mfma_f32_16x16x32_bf16(
              am[fi], bh[fj][ks], dot[fi][fj], 0, 0, 0);      // mh
          dot[fi][fj] = __builtin_amdgcn_mfma_f32_16x16x32_bf16(
              ah[fi], bl_[fj][ks], dot[fi][fj], 0, 0, 0);     // hl
          dot[fi][fj] = __builtin_amdgcn_mfma_f32_16x16x32_bf16(
              am[fi], bm_[fj][ks], dot[fi][fj], 0, 0, 0);     // mm
          dot[fi][fj] = __builtin_amdgcn_mfma_f32_16x16x32_bf16(
              al[fi], bh[fj][ks], dot[fi][fj], 0, 0, 0);      // lh
        }
    }
#pragma unroll
    for (int fi = 0; fi < 2; ++fi) {
      float wv[4];
#pragma unroll
      for (int r = 0; r < 4; ++r) wv[r] = wls[wm + fi * 16 + rg * 4 + r][h];
#pragma unroll
      for (int fj = 0; fj < 2; ++fj)
#pragma unroll
        for (int r = 0; r < 4; ++r)
          acc[fi][fj][r] += fmaxf(dot[fi][fj][r], 0.f) * wv[r];
    }
  }
#pragma unroll
  for (int fi = 0; fi < 2; ++fi)
#pragma unroll
    for (int fj = 0; fj < 2; ++fj)
#pragma unroll
      for (int r = 0; r < 4; ++r) {
        int q = q0 + wm + fi * 16 + rg * 4 + r;
        int k = k0 + wn + fj * 16 + lr;
        if (k <= q) sc[(long)q * (q + 1) / 2 + k] = acc[fi][fj][r];
      }
}

// ---- fallback VALU indexer (if ws too small for splits) --------------------
__global__ __launch_bounds__(256) void idx_scores(
    const float* __restrict__ qb, const float* __restrict__ ikb,
    const float* __restrict__ wb, float* __restrict__ sc) {
  int b = blockIdx.x;
  int tq = (int)((sqrtf(8.f * b + 1.f) - 1.f) * 0.5f);
  while ((tq * (tq + 1)) / 2 > b) --tq;
  while (((tq + 1) * (tq + 2)) / 2 <= b) ++tq;
  int tk = b - (tq * (tq + 1)) / 2;
  int q0 = tq * 64, k0 = tk * 64;
  __shared__ float As0[64][68];
  __shared__ float As1[64][68];
  __shared__ float Bs[64][68];
  __shared__ float wls[64][17];
  int tid = threadIdx.x;
  int lc = tid & 15, lr = tid >> 4;
  int tx = lc, ty = lr;
#pragma unroll
  for (int c = 0; c < 4; ++c) {
    int d = c * 16 + lc;
#pragma unroll
    for (int i = 0; i < 4; ++i)
      Bs[d][lr + 16 * i] = ikb[(long)(k0 + lr + 16 * i) * 64 + d];
  }
#pragma unroll
  for (int i = 0; i < 4; ++i)
    wls[lr + 16 * i][lc] = wb[(long)(q0 + lr + 16 * i) * 16 + lc] * 0.25f;
  float pf0[16], pf1[16];
#pragma unroll
  for (int c = 0; c < 4; ++c)
#pragma unroll
    for (int i = 0; i < 4; ++i) {
      long base = (long)(q0 + lr + 16 * i) * 1024 + c * 16 + lc;
      pf0[c * 4 + i] = qb[base];
      pf1[c * 4 + i] = qb[base + 64];
    }
  float acc[4][4] = {};
  for (int hp = 0; hp < 8; ++hp) {
    __syncthreads();
#pragma unroll
    for (int c = 0; c < 4; ++c)
#pragma unroll
      for (int i = 0; i < 4; ++i) {
        As0[c * 16 + lc][lr + 16 * i] = pf0[c * 4 + i];
        As1[c * 16 + lc][lr + 16 * i] = pf1[c * 4 + i];
      }
    if (hp < 7) {
#pragma unroll
      for (int c = 0; c < 4; ++c)
#pragma unroll
        for (int i = 0; i < 4; ++i) {
          long base =
              (long)(q0 + lr + 16 * i) * 1024 + (2 * hp + 2) * 64 + c * 16 + lc;
          pf0[c * 4 + i] = qb[base];
          pf1[c * 4 + i] = qb[base + 64];
        }
    }
    __syncthreads();
    float wv0[4], wv1[4];
#pragma unroll
    for (int i = 0; i < 4; ++i) {
      wv0[i] = wls[ty * 4 + i][2 * hp];
      wv1[i] = wls[ty * 4 + i][2 * hp + 1];
    }
    float dot0[4][4] = {}, dot1[4][4] = {};
#pragma unroll
    for (int kk = 0; kk < 64; ++kk) {
      float4 a0 = *(const float4*)&As0[kk][ty * 4];
      float4 a1 = *(const float4*)&As1[kk][ty * 4];
      float4 b4 = *(const float4*)&Bs[kk][tx * 4];
      float av0[4] = {a0.x, a0.y, a0.z, a0.w};
      float av1[4] = {a1.x, a1.y, a1.z, a1.w};
      float bv[4] = {b4.x, b4.y, b4.z, b4.w};
#pragma unroll
      for (int i = 0; i < 4; ++i)
#pragma unroll
        for (int j = 0; j < 4; ++j) {
          dot0[i][j] += av0[i] * bv[j];
          dot1[i][j] += av1[i] * bv[j];
        }
    }
#pragma unroll
    for (int i = 0; i < 4; ++i)
#pragma unroll
      for (int j = 0; j < 4; ++j) {
        acc[i][j] += fmaxf(dot0[i][j], 0.f) * wv0[i];
        acc[i][j] += fmaxf(dot1[i][j], 0.f) * wv1[i];
      }
  }
#pragma unroll
  for (int i = 0; i < 4; ++i) {
    int q = q0 + ty * 4 + i;
    long base = (long)q * (q + 1) / 2;
#pragma unroll
    for (int j = 0; j < 4; ++j) {
      int k = k0 + tx * 4 + j;
      if (k <= q) sc[base + k] = acc[i][j];
    }
  }
}

// ---- exact top-128 per row, one wave per row -------------------------------
__device__ inline unsigned fkey(float f) {
  unsigned u = __float_as_uint(f);
  return (u & 0x80000000u) ? ~u : (u | 0x80000000u);
}

__global__ __launch_bounds__(64) void topk_rows(
    const float* __restrict__ sc, int* __restrict__ tidx,
    int* __restrict__ tcnt) {
  int qi = blockIdx.x;
  int lane = threadIdx.x;
  if (qi < TOPK) {
    for (int i = lane; i <= qi; i += 64) tidx[(long)qi * TOPK + i] = i;
    if (lane == 0) tcnt[qi] = qi + 1;
    return;
  }
  const float* row = sc + (long)qi * (qi + 1) / 2;
  unsigned keys[32];
#pragma unroll
  for (int i = 0; i < 32; ++i) {
    int k = lane + 64 * i;
    keys[i] = (k <= qi) ? fkey(row[k] + 0.f) : 0u;
  }
  unsigned lo = 0u, hi = 0xFFFFFFFEu;
  while (lo < hi) {
    unsigned mid = lo + ((hi - lo + 1) >> 1);
    int cnt = 0;
#pragma unroll
    for (int i = 0; i < 32; ++i) cnt += (keys[i] >= mid) ? 1 : 0;
    for (int off = 32; off; off >>= 1) cnt += __shfl_xor(cnt, off);
    if (cnt >= TOPK) lo = mid; else hi = mid - 1;
  }
  unsigned T = lo;
  __shared__ int c1;
  if (lane == 0) c1 = 0;
  __syncthreads();
#pragma unroll
  for (int i = 0; i < 32; ++i) {
    if (keys[i] > T) {
      int pos = atomicAdd(&c1, 1);
      tidx[(long)qi * TOPK + pos] = lane + 64 * i;
    }
  }
  __syncthreads();
  int c = c1;
  for (int i = 0; i < 32 && c < TOPK; ++i) {
    unsigned long long m = __ballot(keys[i] == T);
    while (m && c < TOPK) {
      int l = __ffsll(m) - 1;
      m &= m - 1;
      if (lane == 0) tidx[(long)qi * TOPK + c] = 64 * i + l;
      ++c;
    }
  }
  if (lane == 0) tcnt[qi] = TOPK;
}

// ---- sparse attention: block (q, kvh); 4 waves; K staged as bf16 in LDS ----
__global__ __launch_bounds__(256) void sparse_attn(
    const float* __restrict__ qb, const short* __restrict__ kb_bf,
    const float* __restrict__ vb, const int* __restrict__ tidx,
    const int* __restrict__ tcnt, short* __restrict__ attn) {
  int kvh = blockIdx.x;
  int qi  = blockIdx.y;
  int tid = threadIdx.x, lane = tid & 63, w = tid >> 6;
  int h = kvh * 4 + w;
  int cnt = tcnt[qi];
  __shared__ int   idxs[128];
  __shared__ short Ks[128][68] __attribute__((aligned(16)));
  __shared__ float qs[4][64];
  __shared__ float ps[4][128];
  if (tid < 128) idxs[tid] = (tid < cnt) ? tidx[(long)qi * TOPK + tid] : 0;
  qs[w][lane] = qb[(long)qi * 1024 + h * 64 + lane];
  __syncthreads();
  {
    int j0 = tid >> 2, qf = tid & 3;     // 4 threads per K row (coalesced)
#pragma unroll
    for (int pass = 0; pass < 2; ++pass) {
      int j = j0 + pass * 64;
      if (j < cnt) {
        int ki = idxs[j];
        const short* kr = kb_bf + (long)ki * 256 + kvh * 64 + qf * 16;
        short8 k0 = *(const short8*)(kr);
        short8 k1 = *(const short8*)(kr + 8);
        *(short4*)&Ks[j][qf * 16 + 0]  = *(short4*)&k0;
        *(short4*)&Ks[j][qf * 16 + 4]  = *((short4*)&k0 + 1);
        *(short4*)&Ks[j][qf * 16 + 8]  = *(short4*)&k1;
        *(short4*)&Ks[j][qf * 16 + 12] = *((short4*)&k1 + 1);
      }
    }
  }
  __syncthreads();
  float4 qreg[16];
#pragma unroll
  for (int c = 0; c < 16; ++c) qreg[c] = *(const float4*)&qs[w][c * 4];
  float l0 = -INFINITY, l1 = -INFINITY;
#pragma unroll
  for (int slot = 0; slot < 2; ++slot) {
    int j = lane + slot * 64;
    if (j < cnt) {
      float d = 0.f;
#pragma unroll
      for (int c = 0; c < 16; ++c) {
        short4 kk4 = *(const short4*)&Ks[j][c * 4];
        d += qreg[c].x * bf2f(kk4.x);
        d += qreg[c].y * bf2f(kk4.y);
        d += qreg[c].z * bf2f(kk4.z);
        d += qreg[c].w * bf2f(kk4.w);
      }
      float l = d * 0.125f;
      if (slot == 0) l0 = l; else l1 = l;
    }
  }
  float m = fmaxf(l0, l1);
  for (int off = 32; off; off >>= 1) m = fmaxf(m, __shfl_xor(m, off));
  float p0 = expf(l0 - m), p1 = expf(l1 - m);
  float ssum = p0 + p1;
  for (int off = 32; off; off >>= 1) ssum += __shfl_xor(ssum, off);
  ps[w][lane] = p0;
  ps[w][lane + 64] = p1;
  __syncthreads();
  int sub = lane >> 4, quad = lane & 15;
  float4 o4 = {0.f, 0.f, 0.f, 0.f};
#pragma unroll 4
  for (int j = sub; j < cnt; j += 4) {
    int ki = idxs[j];
    float p = ps[w][j];
    float4 vv = *(const float4*)(vb + (long)ki * 256 + kvh * 64 + quad * 4);
    o4.x += p * vv.x; o4.y += p * vv.y;
    o4.z += p * vv.z; o4.w += p * vv.w;
  }
#pragma unroll
  for (int off = 16; off <= 32; off <<= 1) {
    o4.x += __shfl_xor(o4.x, off);
    o4.y += __shfl_xor(o4.y, off);
    o4.z += __shfl_xor(o4.z, off);
    o4.w += __shfl_xor(o4.w, off);
  }
  if (sub == 0) {
    float inv = 1.f / ssum;
    short4 ov;
    ov.x = f2bf_bits(o4.x * inv); ov.y = f2bf_bits(o4.y * inv);
    ov.z = f2bf_bits(o4.z * inv); ov.w = f2bf_bits(o4.w * inv);
    *(short4*)&attn[(long)qi * 1024 + h * 64 + quad * 4] = ov;
  }
}

// ---- f32 -> bf16 (hi only), standalone for Wo -----------------------------
__global__ __launch_bounds__(256) void conv_hi(
    const float* __restrict__ src, short* __restrict__ dst, int n4) {
  int i = blockIdx.x * 256 + threadIdx.x;
  if (i >= n4) return;
  float4 v = *(const float4*)(src + (long)i * 4);
  short4 hv;
  hv.x = f2bf_bits(v.x); hv.y = f2bf_bits(v.y);
  hv.z = f2bf_bits(v.z); hv.w = f2bf_bits(v.w);
  *(short4*)&dst[(long)i * 4] = hv;
}

// ---------------------------------------------------------------------------
extern "C" void kernel_launch(void* const* d_in, const int* in_sizes, int n_in,
                              void* d_out, int out_size, void* d_ws,
                              size_t ws_size, hipStream_t stream) {
  const float* hs   = (const float*)d_in[0];
  const float* cosb = (const float*)d_in[1];
  const float* sinb = (const float*)d_in[2];
  const float* Wq   = (const float*)d_in[3];
  const float* bq   = (const float*)d_in[4];
  const float* Wk   = (const float*)d_in[5];
  const float* bk   = (const float*)d_in[6];
  const float* Wv   = (const float*)d_in[7];
  const float* bv   = (const float*)d_in[8];
  const float* Wo   = (const float*)d_in[9];
  const float* Wik  = (const float*)d_in[10];
  const float* bik  = (const float*)d_in[11];
  const float* Wiw  = (const float*)d_in[12];
  const float* biw  = (const float*)d_in[13];
  float* out = (float*)d_out;

  float* ws = (float*)d_ws;
  float* qb   = ws;  ws += (long)SEQ * 1024;
  float* kb   = ws;  ws += (long)SEQ * 256;
  float* vb   = ws;  ws += (long)SEQ * 256;
  float* ikb  = ws;  ws += (long)SEQ * 64;
  float* wb   = ws;  ws += (long)SEQ * 16;
  int* tidx   = (int*)ws;  ws += (long)SEQ * TOPK;
  int* tcnt   = (int*)ws;  ws += SEQ;
  short* kb_bf = (short*)ws; ws += (long)SEQ * 128;   // S x 256 bf16 = 1 MB
  float* R1   = ws;  ws += (long)SEQ * (SEQ + 1) / 2;
  float* R2   = ws;  ws += (long)1104 * 1024;
  float* R3   = ws;  ws += 3L * SEQ * 512;         // q_h/m/l: 3 x 2M shorts
  size_t need_big = (size_t)(ws - (float*)d_ws) * 4;   // ~40.8 MB
  int big = ws_size >= need_big;

  short* A_cat   = (short*)R1;          // 8 MB (dead before scores)
  float* scores  = R1;
  short* Wh      = (short*)R2;
  short* Wl      = Wh + (long)1104 * 1024;
  short* attn_bf = (short*)R2;          // Wh/Wl dead by then
  short* Wkv_bf  = (short*)tidx;        // dead before tidx written
  short* Wo_bf   = (short*)qb;          // qb dead after sparse_attn
  short* q_h     = (short*)R3;          // 4 MB each
  short* q_m     = q_h + (long)SEQ * 1024;
  short* q_l     = q_m + (long)SEQ * 1024;
  short* ik_h    = (short*)tidx;        // 3 x 256KB <= 1MB
  short* ik_m    = ik_h + (long)SEQ * 64;
  short* ik_l    = ik_m + (long)SEQ * 64;

  dim3 blk(256);
  conv_all<<<3664, blk, 0, stream>>>(hs, Wq, Wik, Wiw, Wk, Wv, A_cat, Wh, Wl,
                                     Wkv_bf);
  gemm_all<<<dim3(26, 32), blk, 0, stream>>>(A_cat, Wh, Wl, Wkv_bf, bq, bik,
                                             biw, bk, bv, qb, ikb, wb, kb, vb);

  int nrope = SEQ * (NH + NKV + 1) * 32;
  rope_kernel<<<(nrope + 255) / 256, blk, 0, stream>>>(
      qb, kb, ikb, kb_bf, q_h, q_m, q_l, ik_h, ik_m, ik_l, big, cosb, sinb);

  if (big) {
    idx_mfma6<<<528, blk, 0, stream>>>(q_h, q_m, q_l, ik_h, ik_m, ik_l, wb,
                                       scores);
  } else {
    idx_scores<<<528, blk, 0, stream>>>(qb, ikb, wb, scores);
  }
  topk_rows<<<SEQ, dim3(64), 0, stream>>>(scores, tidx, tcnt);

  sparse_attn<<<dim3(NKV, SEQ), blk, 0, stream>>>(qb, kb_bf, vb, tidx, tcnt,
                                                  attn_bf);

  conv_hi<<<1024, blk, 0, stream>>>(Wo, Wo_bf, 1024 * 256);
  gemm_wo<<<dim3(16, 32), blk, 0, stream>>>(attn_bf, Wo_bf, out);
}

// Round 28
// 185.713 us; speedup vs baseline: 1.2412x; 1.0255x over previous
//
#include <hip/hip_runtime.h>
#include <hip/hip_bf16.h>
#include <math.h>

#define SEQ   2048
#define HDIM  1024
#define NH    16
#define NKV   4
#define DHEAD 64
#define TOPK  128

typedef __attribute__((ext_vector_type(8))) short short8;
typedef __attribute__((ext_vector_type(4))) float f32x4;

__device__ inline short f2bf_bits(float x) {          // RTN-even f32 -> bf16
  unsigned u = __float_as_uint(x);
  unsigned r = (u + 0x7FFFu + ((u >> 16) & 1u)) >> 16;
  return (short)r;
}
__device__ inline float bf2f(short s) {
  return __uint_as_float(((unsigned)(unsigned short)s) << 16);
}
__device__ inline void split3(float x, short& h, short& m, short& l) {
  h = f2bf_bits(x);
  float r1 = x - bf2f(h);
  m = f2bf_bits(r1);
  l = f2bf_bits(r1 - bf2f(m));
}

// ---- fused conversions: one dispatch, segmented grid -----------------------
__global__ __launch_bounds__(256) void conv_all(
    const float* __restrict__ hs, const float* __restrict__ Wq,
    const float* __restrict__ Wik, const float* __restrict__ Wiw,
    const float* __restrict__ Wk, const float* __restrict__ Wv,
    short* __restrict__ A_cat, short* __restrict__ Wh, short* __restrict__ Wl,
    short* __restrict__ Wkv) {
  int bb = blockIdx.x;
  int t = threadIdx.x;
  if (bb < 2048) {                          // hs split -> concat rows
    int i = bb * 256 + t;
    float4 v = *(const float4*)(hs + (long)i * 4);
    int r = i >> 8, c = (i & 255) * 4;
    short4 hv, lv;
    short h0 = f2bf_bits(v.x), h1 = f2bf_bits(v.y);
    short h2 = f2bf_bits(v.z), h3 = f2bf_bits(v.w);
    hv.x = h0; hv.y = h1; hv.z = h2; hv.w = h3;
    lv.x = f2bf_bits(v.x - bf2f(h0)); lv.y = f2bf_bits(v.y - bf2f(h1));
    lv.z = f2bf_bits(v.z - bf2f(h2)); lv.w = f2bf_bits(v.w - bf2f(h3));
    *(short4*)&A_cat[(long)r * 2048 + c] = hv;
    *(short4*)&A_cat[(long)r * 2048 + 1024 + c] = lv;
    return;
  }
  const float* src; short *dhi, *dlo; int i;
  if (bb < 3072)      { src = Wq;  dhi = Wh; dlo = Wl;
                        i = (bb - 2048) * 256 + t; }
  else if (bb < 3136) { src = Wik; dhi = Wh + (long)1024 * 1024;
                        dlo = Wl + (long)1024 * 1024;
                        i = (bb - 3072) * 256 + t; }
  else if (bb < 3152) { src = Wiw; dhi = Wh + (long)1088 * 1024;
                        dlo = Wl + (long)1088 * 1024;
                        i = (bb - 3136) * 256 + t; }
  else if (bb < 3408) { src = Wk;  dhi = Wkv; dlo = nullptr;
                        i = (bb - 3152) * 256 + t; }
  else                { src = Wv;  dhi = Wkv + (long)256 * 1024; dlo = nullptr;
                        i = (bb - 3408) * 256 + t; }
  float4 v = *(const float4*)(src + (long)i * 4);
  short4 hv;
  short h0 = f2bf_bits(v.x), h1 = f2bf_bits(v.y);
  short h2 = f2bf_bits(v.z), h3 = f2bf_bits(v.w);
  hv.x = h0; hv.y = h1; hv.z = h2; hv.w = h3;
  *(short4*)&dhi[(long)i * 4] = hv;
  if (dlo) {
    short4 lv;
    lv.x = f2bf_bits(v.x - bf2f(h0)); lv.y = f2bf_bits(v.y - bf2f(h1));
    lv.z = f2bf_bits(v.z - bf2f(h2)); lv.w = f2bf_bits(v.w - bf2f(h3));
    *(short4*)&dlo[(long)i * 4] = lv;
  }
}

// ---- fused projection GEMM: BM=64, BN=64, grid (26, 32); XCD swizzle -------
__global__ __launch_bounds__(256) void gemm_all(
    const short* __restrict__ A_cat, const short* __restrict__ Wh,
    const short* __restrict__ Wl, const short* __restrict__ Wkv,
    const float* __restrict__ bq, const float* __restrict__ bik,
    const float* __restrict__ biw, const float* __restrict__ bk,
    const float* __restrict__ bv, float* __restrict__ qb,
    float* __restrict__ ikb, float* __restrict__ wb, float* __restrict__ kb,
    float* __restrict__ vb) {
  __shared__ short Als[64 * 64] __attribute__((aligned(16)));
  __shared__ short Bls[64 * 64] __attribute__((aligned(16)));
  // XCD-aware bijective swizzle: 832 blocks = 8 XCD x 104; each XCD gets a
  // contiguous id2 range = 4 m-panels -> A-panel L2 locality.
  int flat = blockIdx.x + blockIdx.y * 26;
  int id2 = (flat & 7) * 104 + (flat >> 3);
  int bx = id2 % 26;
  int m0 = (id2 / 26) * 64;
  bool sens = bx < 18;
  int n0 = (sens ? bx : bx - 18) * 64;
  int Nrows = sens ? 1104 : 512;
  int nterm = sens ? 3 : 1;
  int tid = threadIdx.x;
  int lane = tid & 63, wid = tid >> 6;
  int wm = (wid >> 1) * 32, wn = (wid & 1) * 32;   // wave: 32x32 output
  int lr = lane & 15, kg = lane >> 4;
  int arow = tid >> 2, aseg4 = tid & 3;
  int abase = arow * 64 + aseg4 * 16;
  int aswz = (arow & 7) * 8;
  bool bok = (n0 + arow) < Nrows;

  f32x4 acc[2][2] = {};
  for (int term = 0; term < nterm; ++term) {
    const short* Ab = A_cat + (term == 1 ? 1024 : 0);
    const short* Bb = sens ? (term == 2 ? Wl : Wh) : Wkv;
    const short* aseg = Ab + (long)(m0 + arow) * 2048 + aseg4 * 16;
    const short* bseg = Bb + (long)(n0 + arow) * 1024 + aseg4 * 16;
    short8 a0, a1, b0, b1;
    a0 = *(const short8*)(aseg);
    a1 = *(const short8*)(aseg + 8);
    b0 = bok ? *(const short8*)(bseg) : short8{};
    b1 = bok ? *(const short8*)(bseg + 8) : short8{};
    for (int t = 0; t < 16; ++t) {
      __syncthreads();
      *(short8*)&Als[abase ^ aswz] = a0;
      *(short8*)&Als[(abase + 8) ^ aswz] = a1;
      *(short8*)&Bls[abase ^ aswz] = b0;
      *(short8*)&Bls[(abase + 8) ^ aswz] = b1;
      __syncthreads();
      if (t + 1 < 16) {
        const short* an = aseg + (t + 1) * 64;
        const short* bn = bseg + (t + 1) * 64;
        a0 = *(const short8*)(an);
        a1 = *(const short8*)(an + 8);
        b0 = bok ? *(const short8*)(bn) : short8{};
        b1 = bok ? *(const short8*)(bn + 8) : short8{};
      }
#pragma unroll
      for (int kk = 0; kk < 2; ++kk) {
        short8 af[2], bf[2];
#pragma unroll
        for (int f = 0; f < 2; ++f) {
          int ar = wm + f * 16 + lr;
          af[f] = *(short8*)&Als[(ar * 64 + kk * 32 + kg * 8) ^ ((ar & 7) * 8)];
          int br = wn + f * 16 + lr;
          bf[f] = *(short8*)&Bls[(br * 64 + kk * 32 + kg * 8) ^ ((br & 7) * 8)];
        }
#pragma unroll
        for (int fi = 0; fi < 2; ++fi)
#pragma unroll
          for (int fj = 0; fj < 2; ++fj)
            acc[fi][fj] = __builtin_amdgcn_mfma_f32_16x16x32_bf16(
                af[fi], bf[fj], acc[fi][fj], 0, 0, 0);
      }
    }
  }
  int rg = lane >> 4;
#pragma unroll
  for (int fi = 0; fi < 2; ++fi)
#pragma unroll
    for (int fj = 0; fj < 2; ++fj)
#pragma unroll
      for (int r = 0; r < 4; ++r) {
        int gm = m0 + wm + fi * 16 + rg * 4 + r;
        int gn = n0 + wn + fj * 16 + lr;
        float v = acc[fi][fj][r];
        if (sens) {
          if (gn < 1024)      qb[(long)gm * 1024 + gn] = v + bq[gn];
          else if (gn < 1088) ikb[(long)gm * 64 + gn - 1024] = v + bik[gn - 1024];
          else if (gn < 1104) wb[(long)gm * 16 + gn - 1088] = v + biw[gn - 1088];
        } else {
          if (gn < 256) kb[(long)gm * 256 + gn] = v + bk[gn];
          else          vb[(long)gm * 256 + gn - 256] = v + bv[gn - 256];
        }
      }
}

// ---- Wo bf16 GEMM: BM=64, BN=64, grid (16, 32); XCD swizzle ----------------
__global__ __launch_bounds__(256) void gemm_wo(
    const short* __restrict__ A, const short* __restrict__ Bm,
    float* __restrict__ out) {
  __shared__ short Als[64 * 64] __attribute__((aligned(16)));
  __shared__ short Bls[64 * 64] __attribute__((aligned(16)));
  int flat = blockIdx.x + blockIdx.y * 16;   // 512 blocks = 8 XCD x 64
  int id2 = (flat & 7) * 64 + (flat >> 3);
  int n0 = (id2 % 16) * 64;
  int m0 = (id2 / 16) * 64;
  int tid = threadIdx.x;
  int lane = tid & 63, wid = tid >> 6;
  int wm = (wid >> 1) * 32, wn = (wid & 1) * 32;
  int lr = lane & 15, kg = lane >> 4;
  int arow = tid >> 2, aseg4 = tid & 3;
  int abase = arow * 64 + aseg4 * 16;
  int aswz = (arow & 7) * 8;
  const short* aseg = A + (long)(m0 + arow) * 1024 + aseg4 * 16;
  const short* bseg = Bm + (long)(n0 + arow) * 1024 + aseg4 * 16;
  f32x4 acc[2][2] = {};
  short8 a0, a1, b0, b1;
  a0 = *(const short8*)(aseg);
  a1 = *(const short8*)(aseg + 8);
  b0 = *(const short8*)(bseg);
  b1 = *(const short8*)(bseg + 8);
  for (int t = 0; t < 16; ++t) {
    __syncthreads();
    *(short8*)&Als[abase ^ aswz] = a0;
    *(short8*)&Als[(abase + 8) ^ aswz] = a1;
    *(short8*)&Bls[abase ^ aswz] = b0;
    *(short8*)&Bls[(abase + 8) ^ aswz] = b1;
    __syncthreads();
    if (t + 1 < 16) {
      const short* an = aseg + (t + 1) * 64;
      const short* bn = bseg + (t + 1) * 64;
      a0 = *(const short8*)(an);
      a1 = *(const short8*)(an + 8);
      b0 = *(const short8*)(bn);
      b1 = *(const short8*)(bn + 8);
    }
#pragma unroll
    for (int kk = 0; kk < 2; ++kk) {
      short8 af[2], bf[2];
#pragma unroll
      for (int f = 0; f < 2; ++f) {
        int ar = wm + f * 16 + lr;
        af[f] = *(short8*)&Als[(ar * 64 + kk * 32 + kg * 8) ^ ((ar & 7) * 8)];
        int br = wn + f * 16 + lr;
        bf[f] = *(short8*)&Bls[(br * 64 + kk * 32 + kg * 8) ^ ((br & 7) * 8)];
      }
#pragma unroll
      for (int fi = 0; fi < 2; ++fi)
#pragma unroll
        for (int fj = 0; fj < 2; ++fj)
          acc[fi][fj] = __builtin_amdgcn_mfma_f32_16x16x32_bf16(
              af[fi], bf[fj], acc[fi][fj], 0, 0, 0);
    }
  }
  int rg = lane >> 4;
#pragma unroll
  for (int fi = 0; fi < 2; ++fi)
#pragma unroll
    for (int fj = 0; fj < 2; ++fj)
#pragma unroll
      for (int r = 0; r < 4; ++r) {
        int gm = m0 + wm + fi * 16 + rg * 4 + r;
        int gn = n0 + wn + fj * 16 + lr;
        out[(long)gm * 1024 + gn] = acc[fi][fj][r];
      }
}

// ---- RoPE + fused 3-way splits (q,ik) + bf16 K copy ------------------------
__global__ void rope_kernel(float* __restrict__ q, float* __restrict__ k,
                            float* __restrict__ ik, short* __restrict__ k_bf,
                            short* __restrict__ qh, short* __restrict__ qm,
                            short* __restrict__ ql, short* __restrict__ ikh,
                            short* __restrict__ ikm, short* __restrict__ ikl,
                            int big,
                            const float* __restrict__ cosb,
                            const float* __restrict__ sinb) {
  int gid = blockIdx.x * 256 + threadIdx.x;
  const int NV = SEQ * (NH + NKV + 1);
  if (gid >= NV * 32) return;
  int p = gid & 31;
  int vec = gid >> 5;
  int s;
  if (vec < SEQ * NH) {                     // q branch
    s = vec / NH; int h = vec % NH;
    long off = (long)s * 1024 + h * 64;
    float c = cosb[s * 64 + p], sn = sinb[s * 64 + p];
    float x1 = q[off + p], x2 = q[off + p + 32];
    float y1 = x1 * c - x2 * sn;
    float y2 = x2 * c + x1 * sn;
    q[off + p] = y1;
    q[off + p + 32] = y2;
    if (big) {
      short h1, m1, l1, h2, m2, l2;
      split3(y1, h1, m1, l1);
      split3(y2, h2, m2, l2);
      qh[off + p] = h1; qm[off + p] = m1; ql[off + p] = l1;
      qh[off + p + 32] = h2; qm[off + p + 32] = m2; ql[off + p + 32] = l2;
    }
  } else if (vec < SEQ * (NH + NKV)) {      // k branch (+ bf16 copy)
    int t = vec - SEQ * NH;
    s = t / NKV; int kh = t % NKV;
    long off = (long)s * 256 + kh * 64;
    float c = cosb[s * 64 + p], sn = sinb[s * 64 + p];
    float x1 = k[off + p], x2 = k[off + p + 32];
    float y1 = x1 * c - x2 * sn;
    float y2 = x2 * c + x1 * sn;
    k[off + p] = y1;
    k[off + p + 32] = y2;
    k_bf[off + p] = f2bf_bits(y1);
    k_bf[off + p + 32] = f2bf_bits(y2);
  } else {                                  // ik branch (+ splits)
    s = vec - SEQ * (NH + NKV);
    long off = (long)s * 64;
    float c = cosb[s * 64 + p], sn = sinb[s * 64 + p];
    float x1 = ik[off + p], x2 = ik[off + p + 32];
    float y1 = x1 * c - x2 * sn;
    float y2 = x2 * c + x1 * sn;
    ik[off + p] = y1;
    ik[off + p + 32] = y2;
    if (big) {
      short h1, m1, l1, h2, m2, l2;
      split3(y1, h1, m1, l1);
      split3(y2, h2, m2, l2);
      ikh[off + p] = h1; ikm[off + p] = m1; ikl[off + p] = l1;
      ikh[off + p + 32] = h2; ikm[off + p + 32] = m2; ikl[off + p + 32] = l2;
    }
  }
}

// ---- MFMA indexer scores, EXACT 3-way split; next-h q prefetched to regs ---
__global__ __launch_bounds__(256) void idx_mfma6(
    const short* __restrict__ q_h, const short* __restrict__ q_m,
    const short* __restrict__ q_l, const short* __restrict__ ik_h,
    const short* __restrict__ ik_m, const short* __restrict__ ik_l,
    const float* __restrict__ wb, float* __restrict__ sc) {
  int b = blockIdx.x;                         // 0..527 triangular
  int tq = (int)((sqrtf(8.f * b + 1.f) - 1.f) * 0.5f);
  while ((tq * (tq + 1)) / 2 > b) --tq;
  while (((tq + 1) * (tq + 2)) / 2 <= b) ++tq;
  int tk = b - (tq * (tq + 1)) / 2;
  int q0 = tq * 64, k0 = tk * 64;

  __shared__ short QH[64 * 64] __attribute__((aligned(16)));
  __shared__ short QM[64 * 64] __attribute__((aligned(16)));
  __shared__ short QL[64 * 64] __attribute__((aligned(16)));
  __shared__ short IH[64 * 64] __attribute__((aligned(16)));
  __shared__ short IM[64 * 64] __attribute__((aligned(16)));
  __shared__ short IL[64 * 64] __attribute__((aligned(16)));
  __shared__ float wls[64][17];

  int tid = threadIdx.x;
  int lane = tid & 63, wid = tid >> 6;
  int wm = (wid >> 1) * 32, wn = (wid & 1) * 32;
  int lr = lane & 15, kg = lane >> 4;
  int sr = tid >> 2, seg = tid & 3;
  int sbase = sr * 64 + seg * 16;
  int sswz = (sr & 7) * 8;

  {  // stage ik tiles (once) + w tile
    const short* g0 = ik_h + (long)(k0 + sr) * 64 + seg * 16;
    const short* g1 = ik_m + (long)(k0 + sr) * 64 + seg * 16;
    const short* g2 = ik_l + (long)(k0 + sr) * 64 + seg * 16;
#pragma unroll
    for (int c = 0; c < 2; ++c) {
      *(short8*)&IH[(sbase + c * 8) ^ sswz] = *(const short8*)(g0 + c * 8);
      *(short8*)&IM[(sbase + c * 8) ^ sswz] = *(const short8*)(g1 + c * 8);
      *(short8*)&IL[(sbase + c * 8) ^ sswz] = *(const short8*)(g2 + c * 8);
    }
    int wlc = tid & 15, wlr = tid >> 4;
#pragma unroll
    for (int i = 0; i < 4; ++i)
      wls[wlr + 16 * i][wlc] = wb[(long)(q0 + wlr + 16 * i) * 16 + wlc] * 0.25f;
  }
  // prefetch q fragments for h=0 into registers
  long qrow = (long)(q0 + sr) * 1024 + seg * 16;
  short8 pa0 = *(const short8*)(q_h + qrow);
  short8 pa1 = *(const short8*)(q_h + qrow + 8);
  short8 pb0 = *(const short8*)(q_m + qrow);
  short8 pb1 = *(const short8*)(q_m + qrow + 8);
  short8 pc0 = *(const short8*)(q_l + qrow);
  short8 pc1 = *(const short8*)(q_l + qrow + 8);
  __syncthreads();
  short8 bh[2][2], bm_[2][2], bl_[2][2];
#pragma unroll
  for (int fj = 0; fj < 2; ++fj)
#pragma unroll
    for (int ks = 0; ks < 2; ++ks) {
      int br = wn + fj * 16 + lr;
      int idx = (br * 64 + ks * 32 + kg * 8) ^ ((br & 7) * 8);
      bh[fj][ks] = *(short8*)&IH[idx];
      bm_[fj][ks] = *(short8*)&IM[idx];
      bl_[fj][ks] = *(short8*)&IL[idx];
    }

  int rg = lane >> 4;
  f32x4 acc[2][2] = {};
  for (int h = 0; h < NH; ++h) {
    __syncthreads();                       // prior h's A-frag reads done
    *(short8*)&QH[sbase ^ sswz] = pa0;
    *(short8*)&QH[(sbase + 8) ^ sswz] = pa1;
    *(short8*)&QM[sbase ^ sswz] = pb0;
    *(short8*)&QM[(sbase + 8) ^ sswz] = pb1;
    *(short8*)&QL[sbase ^ sswz] = pc0;
    *(short8*)&QL[(sbase + 8) ^ sswz] = pc1;
    if (h + 1 < NH) {                      // prefetch next h (hidden by MFMA)
      long nrow = qrow + (h + 1) * 64;
      pa0 = *(const short8*)(q_h + nrow);
      pa1 = *(const short8*)(q_h + nrow + 8);
      pb0 = *(const short8*)(q_m + nrow);
      pb1 = *(const short8*)(q_m + nrow + 8);
      pc0 = *(const short8*)(q_l + nrow);
      pc1 = *(const short8*)(q_l + nrow + 8);
    }
    __syncthreads();
    f32x4 dot[2][2] = {};
#pragma unroll
    for (int ks = 0; ks < 2; ++ks) {
      short8 ah[2], am[2], al[2];
#pragma unroll
      for (int fi = 0; fi < 2; ++fi) {
        int ar = wm + fi * 16 + lr;
        int idx = (ar * 64 + ks * 32 + kg * 8) ^ ((ar & 7) * 8);
        ah[fi] = *(short8*)&QH[idx];
        am[fi] = *(short8*)&QM[idx];
        al[fi] = *(short8*)&QL[idx];
      }
#pragma unroll
      for (int fi = 0; fi < 2; ++fi)
#pragma unroll
        for (int fj = 0; fj < 2; ++fj) {
          dot[fi][fj] = __builtin_amdgcn_mfma_f32_16x16x32_bf16(
              ah[fi], bh[fj][ks], dot[fi][fj], 0, 0, 0);      // hh
          dot[fi][fj] = __builtin_amdgcn_mfma_f32_16x16x32_bf16(
              ah[fi], bm_[fj][ks], dot[fi][fj], 0, 0, 0);     // hm
          dot[fi][fj] = __builtin_amdgcn_mfma_f32_16x16x32_bf16(
              am[fi], bh[fj][ks], dot[fi][fj], 0, 0, 0);      // mh
          dot[fi][fj] = __builtin_amdgcn_mfma_f32_16x16x32_bf16(
              ah[fi], bl_[fj][ks], dot[fi][fj], 0, 0, 0);     // hl
          dot[fi][fj] = __builtin_amdgcn_mfma_f32_16x16x32_bf16(
              am[fi], bm_[fj][ks], dot[fi][fj], 0, 0, 0);     // mm
          dot[fi][fj] = __builtin_amdgcn_mfma_f32_16x16x32_bf16(
              al[fi], bh[fj][ks], dot[fi][fj], 0, 0, 0);      // lh
        }
    }
#pragma unroll
    for (int fi = 0; fi < 2; ++fi) {
      float wv[4];
#pragma unroll
      for (int r = 0; r < 4; ++r) wv[r] = wls[wm + fi * 16 + rg * 4 + r][h];
#pragma unroll
      for (int fj = 0; fj < 2; ++fj)
#pragma unroll
        for (int r = 0; r < 4; ++r)
          acc[fi][fj][r] += fmaxf(dot[fi][fj][r], 0.f) * wv[r];
    }
  }
#pragma unroll
  for (int fi = 0; fi < 2; ++fi)
#pragma unroll
    for (int fj = 0; fj < 2; ++fj)
#pragma unroll
      for (int r = 0; r < 4; ++r) {
        int q = q0 + wm + fi * 16 + rg * 4 + r;
        int k = k0 + wn + fj * 16 + lr;
        if (k <= q) sc[(long)q * (q + 1) / 2 + k] = acc[fi][fj][r];
      }
}

// ---- fallback VALU indexer (if ws too small for splits) --------------------
__global__ __launch_bounds__(256) void idx_scores(
    const float* __restrict__ qb, const float* __restrict__ ikb,
    const float* __restrict__ wb, float* __restrict__ sc) {
  int b = blockIdx.x;
  int tq = (int)((sqrtf(8.f * b + 1.f) - 1.f) * 0.5f);
  while ((tq * (tq + 1)) / 2 > b) --tq;
  while (((tq + 1) * (tq + 2)) / 2 <= b) ++tq;
  int tk = b - (tq * (tq + 1)) / 2;
  int q0 = tq * 64, k0 = tk * 64;
  __shared__ float As0[64][68];
  __shared__ float As1[64][68];
  __shared__ float Bs[64][68];
  __shared__ float wls[64][17];
  int tid = threadIdx.x;
  int lc = tid & 15, lr = tid >> 4;
  int tx = lc, ty = lr;
#pragma unroll
  for (int c = 0; c < 4; ++c) {
    int d = c * 16 + lc;
#pragma unroll
    for (int i = 0; i < 4; ++i)
      Bs[d][lr + 16 * i] = ikb[(long)(k0 + lr + 16 * i) * 64 + d];
  }
#pragma unroll
  for (int i = 0; i < 4; ++i)
    wls[lr + 16 * i][lc] = wb[(long)(q0 + lr + 16 * i) * 16 + lc] * 0.25f;
  float pf0[16], pf1[16];
#pragma unroll
  for (int c = 0; c < 4; ++c)
#pragma unroll
    for (int i = 0; i < 4; ++i) {
      long base = (long)(q0 + lr + 16 * i) * 1024 + c * 16 + lc;
      pf0[c * 4 + i] = qb[base];
      pf1[c * 4 + i] = qb[base + 64];
    }
  float acc[4][4] = {};
  for (int hp = 0; hp < 8; ++hp) {
    __syncthreads();
#pragma unroll
    for (int c = 0; c < 4; ++c)
#pragma unroll
      for (int i = 0; i < 4; ++i) {
        As0[c * 16 + lc][lr + 16 * i] = pf0[c * 4 + i];
        As1[c * 16 + lc][lr + 16 * i] = pf1[c * 4 + i];
      }
    if (hp < 7) {
#pragma unroll
      for (int c = 0; c < 4; ++c)
#pragma unroll
        for (int i = 0; i < 4; ++i) {
          long base =
              (long)(q0 + lr + 16 * i) * 1024 + (2 * hp + 2) * 64 + c * 16 + lc;
          pf0[c * 4 + i] = qb[base];
          pf1[c * 4 + i] = qb[base + 64];
        }
    }
    __syncthreads();
    float wv0[4], wv1[4];
#pragma unroll
    for (int i = 0; i < 4; ++i) {
      wv0[i] = wls[ty * 4 + i][2 * hp];
      wv1[i] = wls[ty * 4 + i][2 * hp + 1];
    }
    float dot0[4][4] = {}, dot1[4][4] = {};
#pragma unroll
    for (int kk = 0; kk < 64; ++kk) {
      float4 a0 = *(const float4*)&As0[kk][ty * 4];
      float4 a1 = *(const float4*)&As1[kk][ty * 4];
      float4 b4 = *(const float4*)&Bs[kk][tx * 4];
      float av0[4] = {a0.x, a0.y, a0.z, a0.w};
      float av1[4] = {a1.x, a1.y, a1.z, a1.w};
      float bv[4] = {b4.x, b4.y, b4.z, b4.w};
#pragma unroll
      for (int i = 0; i < 4; ++i)
#pragma unroll
        for (int j = 0; j < 4; ++j) {
          dot0[i][j] += av0[i] * bv[j];
          dot1[i][j] += av1[i] * bv[j];
        }
    }
#pragma unroll
    for (int i = 0; i < 4; ++i)
#pragma unroll
      for (int j = 0; j < 4; ++j) {
        acc[i][j] += fmaxf(dot0[i][j], 0.f) * wv0[i];
        acc[i][j] += fmaxf(dot1[i][j], 0.f) * wv1[i];
      }
  }
#pragma unroll
  for (int i = 0; i < 4; ++i) {
    int q = q0 + ty * 4 + i;
    long base = (long)q * (q + 1) / 2;
#pragma unroll
    for (int j = 0; j < 4; ++j) {
      int k = k0 + tx * 4 + j;
      if (k <= q) sc[base + k] = acc[i][j];
    }
  }
}

// ---- exact top-128 per row, one wave per row -------------------------------
__device__ inline unsigned fkey(float f) {
  unsigned u = __float_as_uint(f);
  return (u & 0x80000000u) ? ~u : (u | 0x80000000u);
}

__global__ __launch_bounds__(64) void topk_rows(
    const float* __restrict__ sc, int* __restrict__ tidx,
    int* __restrict__ tcnt) {
  int qi = blockIdx.x;
  int lane = threadIdx.x;
  if (qi < TOPK) {
    for (int i = lane; i <= qi; i += 64) tidx[(long)qi * TOPK + i] = i;
    if (lane == 0) tcnt[qi] = qi + 1;
    return;
  }
  const float* row = sc + (long)qi * (qi + 1) / 2;
  unsigned keys[32];
#pragma unroll
  for (int i = 0; i < 32; ++i) {
    int k = lane + 64 * i;
    keys[i] = (k <= qi) ? fkey(row[k] + 0.f) : 0u;
  }
  unsigned lo = 0u, hi = 0xFFFFFFFEu;
  while (lo < hi) {
    unsigned mid = lo + ((hi - lo + 1) >> 1);
    int cnt = 0;
#pragma unroll
    for (int i = 0; i < 32; ++i) cnt += (keys[i] >= mid) ? 1 : 0;
    for (int off = 32; off; off >>= 1) cnt += __shfl_xor(cnt, off);
    if (cnt >= TOPK) lo = mid; else hi = mid - 1;
  }
  unsigned T = lo;
  __shared__ int c1;
  if (lane == 0) c1 = 0;
  __syncthreads();
#pragma unroll
  for (int i = 0; i < 32; ++i) {
    if (keys[i] > T) {
      int pos = atomicAdd(&c1, 1);
      tidx[(long)qi * TOPK + pos] = lane + 64 * i;
    }
  }
  __syncthreads();
  int c = c1;
  for (int i = 0; i < 32 && c < TOPK; ++i) {
    unsigned long long m = __ballot(keys[i] == T);
    while (m && c < TOPK) {
      int l = __ffsll(m) - 1;
      m &= m - 1;
      if (lane == 0) tidx[(long)qi * TOPK + c] = 64 * i + l;
      ++c;
    }
  }
  if (lane == 0) tcnt[qi] = TOPK;
}

// ---- sparse attention: block (q, kvh); 4 waves; K staged as bf16 in LDS ----
__global__ __launch_bounds__(256) void sparse_attn(
    const float* __restrict__ qb, const short* __restrict__ kb_bf,
    const float* __restrict__ vb, const int* __restrict__ tidx,
    const int* __restrict__ tcnt, short* __restrict__ attn) {
  int kvh = blockIdx.x;
  int qi  = blockIdx.y;
  int tid = threadIdx.x, lane = tid & 63, w = tid >> 6;
  int h = kvh * 4 + w;
  int cnt = tcnt[qi];
  __shared__ int   idxs[128];
  __shared__ short Ks[128][68] __attribute__((aligned(16)));
  __shared__ float qs[4][64];
  __shared__ float ps[4][128];
  if (tid < 128) idxs[tid] = (tid < cnt) ? tidx[(long)qi * TOPK + tid] : 0;
  qs[w][lane] = qb[(long)qi * 1024 + h * 64 + lane];
  __syncthreads();
  {
    int j0 = tid >> 2, qf = tid & 3;     // 4 threads per K row (coalesced)
#pragma unroll
    for (int pass = 0; pass < 2; ++pass) {
      int j = j0 + pass * 64;
      if (j < cnt) {
        int ki = idxs[j];
        const short* kr = kb_bf + (long)ki * 256 + kvh * 64 + qf * 16;
        short8 k0 = *(const short8*)(kr);
        short8 k1 = *(const short8*)(kr + 8);
        *(short4*)&Ks[j][qf * 16 + 0]  = *(short4*)&k0;
        *(short4*)&Ks[j][qf * 16 + 4]  = *((short4*)&k0 + 1);
        *(short4*)&Ks[j][qf * 16 + 8]  = *(short4*)&k1;
        *(short4*)&Ks[j][qf * 16 + 12] = *((short4*)&k1 + 1);
      }
    }
  }
  __syncthreads();
  float4 qreg[16];
#pragma unroll
  for (int c = 0; c < 16; ++c) qreg[c] = *(const float4*)&qs[w][c * 4];
  float l0 = -INFINITY, l1 = -INFINITY;
#pragma unroll
  for (int slot = 0; slot < 2; ++slot) {
    int j = lane + slot * 64;
    if (j < cnt) {
      float d = 0.f;
#pragma unroll
      for (int c = 0; c < 16; ++c) {
        short4 kk4 = *(const short4*)&Ks[j][c * 4];
        d += qreg[c].x * bf2f(kk4.x);
        d += qreg[c].y * bf2f(kk4.y);
        d += qreg[c].z * bf2f(kk4.z);
        d += qreg[c].w * bf2f(kk4.w);
      }
      float l = d * 0.125f;
      if (slot == 0) l0 = l; else l1 = l;
    }
  }
  float m = fmaxf(l0, l1);
  for (int off = 32; off; off >>= 1) m = fmaxf(m, __shfl_xor(m, off));
  float p0 = expf(l0 - m), p1 = expf(l1 - m);
  float ssum = p0 + p1;
  for (int off = 32; off; off >>= 1) ssum += __shfl_xor(ssum, off);
  ps[w][lane] = p0;
  ps[w][lane + 64] = p1;
  __syncthreads();
  int sub = lane >> 4, quad = lane & 15;
  float4 o4 = {0.f, 0.f, 0.f, 0.f};
#pragma unroll 4
  for (int j = sub; j < cnt; j += 4) {
    int ki = idxs[j];
    float p = ps[w][j];
    float4 vv = *(const float4*)(vb + (long)ki * 256 + kvh * 64 + quad * 4);
    o4.x += p * vv.x; o4.y += p * vv.y;
    o4.z += p * vv.z; o4.w += p * vv.w;
  }
#pragma unroll
  for (int off = 16; off <= 32; off <<= 1) {
    o4.x += __shfl_xor(o4.x, off);
    o4.y += __shfl_xor(o4.y, off);
    o4.z += __shfl_xor(o4.z, off);
    o4.w += __shfl_xor(o4.w, off);
  }
  if (sub == 0) {
    float inv = 1.f / ssum;
    short4 ov;
    ov.x = f2bf_bits(o4.x * inv); ov.y = f2bf_bits(o4.y * inv);
    ov.z = f2bf_bits(o4.z * inv); ov.w = f2bf_bits(o4.w * inv);
    *(short4*)&attn[(long)qi * 1024 + h * 64 + quad * 4] = ov;
  }
}

// ---- f32 -> bf16 (hi only), standalone for Wo -----------------------------
__global__ __launch_bounds__(256) void conv_hi(
    const float* __restrict__ src, short* __restrict__ dst, int n4) {
  int i = blockIdx.x * 256 + threadIdx.x;
  if (i >= n4) return;
  float4 v = *(const float4*)(src + (long)i * 4);
  short4 hv;
  hv.x = f2bf_bits(v.x); hv.y = f2bf_bits(v.y);
  hv.z = f2bf_bits(v.z); hv.w = f2bf_bits(v.w);
  *(short4*)&dst[(long)i * 4] = hv;
}

// ---------------------------------------------------------------------------
extern "C" void kernel_launch(void* const* d_in, const int* in_sizes, int n_in,
                              void* d_out, int out_size, void* d_ws,
                              size_t ws_size, hipStream_t stream) {
  const float* hs   = (const float*)d_in[0];
  const float* cosb = (const float*)d_in[1];
  const float* sinb = (const float*)d_in[2];
  const float* Wq   = (const float*)d_in[3];
  const float* bq   = (const float*)d_in[4];
  const float* Wk   = (const float*)d_in[5];
  const float* bk   = (const float*)d_in[6];
  const float* Wv   = (const float*)d_in[7];
  const float* bv   = (const float*)d_in[8];
  const float* Wo   = (const float*)d_in[9];
  const float* Wik  = (const float*)d_in[10];
  const float* bik  = (const float*)d_in[11];
  const float* Wiw  = (const float*)d_in[12];
  const float* biw  = (const float*)d_in[13];
  float* out = (float*)d_out;

  float* ws = (float*)d_ws;
  float* qb   = ws;  ws += (long)SEQ * 1024;
  float* kb   = ws;  ws += (long)SEQ * 256;
  float* vb   = ws;  ws += (long)SEQ * 256;
  float* ikb  = ws;  ws += (long)SEQ * 64;
  float* wb   = ws;  ws += (long)SEQ * 16;
  int* tidx   = (int*)ws;  ws += (long)SEQ * TOPK;
  int* tcnt   = (int*)ws;  ws += SEQ;
  short* kb_bf = (short*)ws; ws += (long)SEQ * 128;   // S x 256 bf16 = 1 MB
  float* R1   = ws;  ws += (long)SEQ * (SEQ + 1) / 2;
  float* R2   = ws;  ws += (long)1104 * 1024;
  float* R3   = ws;  ws += 3L * SEQ * 512;         // q_h/m/l: 3 x 2M shorts
  size_t need_big = (size_t)(ws - (float*)d_ws) * 4;   // ~40.8 MB
  int big = ws_size >= need_big;

  short* A_cat   = (short*)R1;          // 8 MB (dead before scores)
  float* scores  = R1;
  short* Wh      = (short*)R2;
  short* Wl      = Wh + (long)1104 * 1024;
  short* attn_bf = (short*)R2;          // Wh/Wl dead by then
  short* Wkv_bf  = (short*)tidx;        // dead before tidx written
  short* Wo_bf   = (short*)qb;          // qb dead after sparse_attn
  short* q_h     = (short*)R3;          // 4 MB each
  short* q_m     = q_h + (long)SEQ * 1024;
  short* q_l     = q_m + (long)SEQ * 1024;
  short* ik_h    = (short*)tidx;        // 3 x 256KB <= 1MB
  short* ik_m    = ik_h + (long)SEQ * 64;
  short* ik_l    = ik_m + (long)SEQ * 64;

  dim3 blk(256);
  conv_all<<<3664, blk, 0, stream>>>(hs, Wq, Wik, Wiw, Wk, Wv, A_cat, Wh, Wl,
                                     Wkv_bf);
  gemm_all<<<dim3(26, 32), blk, 0, stream>>>(A_cat, Wh, Wl, Wkv_bf, bq, bik,
                                             biw, bk, bv, qb, ikb, wb, kb, vb);

  int nrope = SEQ * (NH + NKV + 1) * 32;
  rope_kernel<<<(nrope + 255) / 256, blk, 0, stream>>>(
      qb, kb, ikb, kb_bf, q_h, q_m, q_l, ik_h, ik_m, ik_l, big, cosb, sinb);

  if (big) {
    idx_mfma6<<<528, blk, 0, stream>>>(q_h, q_m, q_l, ik_h, ik_m, ik_l, wb,
                                       scores);
  } else {
    idx_scores<<<528, blk, 0, stream>>>(qb, ikb, wb, scores);
  }
  topk_rows<<<SEQ, dim3(64), 0, stream>>>(scores, tidx, tcnt);

  sparse_attn<<<dim3(NKV, SEQ), blk, 0, stream>>>(qb, kb_bf, vb, tidx, tcnt,
                                                  attn_bf);

  conv_hi<<<1024, blk, 0, stream>>>(Wo, Wo_bf, 1024 * 256);
  gemm_wo<<<dim3(16, 32), blk, 0, stream>>>(attn_bf, Wo_bf, out);
}

// Round 29
// 183.274 us; speedup vs baseline: 1.2577x; 1.0133x over previous
//
#include <hip/hip_runtime.h>
#include <hip/hip_bf16.h>
#include <math.h>

#define SEQ   2048
#define HDIM  1024
#define NH    16
#define NKV   4
#define DHEAD 64
#define TOPK  128

typedef __attribute__((ext_vector_type(8))) short short8;
typedef __attribute__((ext_vector_type(4))) float f32x4;

__device__ inline short f2bf_bits(float x) {          // RTN-even f32 -> bf16
  unsigned u = __float_as_uint(x);
  unsigned r = (u + 0x7FFFu + ((u >> 16) & 1u)) >> 16;
  return (short)r;
}
__device__ inline float bf2f(short s) {
  return __uint_as_float(((unsigned)(unsigned short)s) << 16);
}
__device__ inline void split3(float x, short& h, short& m, short& l) {
  h = f2bf_bits(x);
  float r1 = x - bf2f(h);
  m = f2bf_bits(r1);
  l = f2bf_bits(r1 - bf2f(m));
}

// ---- fused conversions: one dispatch, segmented grid -----------------------
// seg5 end extended: [3664, 4688) converts Wo -> Wo_bf2 (big path only).
__global__ __launch_bounds__(256) void conv_all(
    const float* __restrict__ hs, const float* __restrict__ Wq,
    const float* __restrict__ Wik, const float* __restrict__ Wiw,
    const float* __restrict__ Wk, const float* __restrict__ Wv,
    const float* __restrict__ Wo,
    short* __restrict__ A_cat, short* __restrict__ Wh, short* __restrict__ Wl,
    short* __restrict__ Wkv, short* __restrict__ Wo_bf2) {
  int bb = blockIdx.x;
  int t = threadIdx.x;
  if (bb < 2048) {                          // hs split -> concat rows
    int i = bb * 256 + t;
    float4 v = *(const float4*)(hs + (long)i * 4);
    int r = i >> 8, c = (i & 255) * 4;
    short4 hv, lv;
    short h0 = f2bf_bits(v.x), h1 = f2bf_bits(v.y);
    short h2 = f2bf_bits(v.z), h3 = f2bf_bits(v.w);
    hv.x = h0; hv.y = h1; hv.z = h2; hv.w = h3;
    lv.x = f2bf_bits(v.x - bf2f(h0)); lv.y = f2bf_bits(v.y - bf2f(h1));
    lv.z = f2bf_bits(v.z - bf2f(h2)); lv.w = f2bf_bits(v.w - bf2f(h3));
    *(short4*)&A_cat[(long)r * 2048 + c] = hv;
    *(short4*)&A_cat[(long)r * 2048 + 1024 + c] = lv;
    return;
  }
  const float* src; short *dhi, *dlo; int i;
  if (bb < 3072)      { src = Wq;  dhi = Wh; dlo = Wl;
                        i = (bb - 2048) * 256 + t; }
  else if (bb < 3136) { src = Wik; dhi = Wh + (long)1024 * 1024;
                        dlo = Wl + (long)1024 * 1024;
                        i = (bb - 3072) * 256 + t; }
  else if (bb < 3152) { src = Wiw; dhi = Wh + (long)1088 * 1024;
                        dlo = Wl + (long)1088 * 1024;
                        i = (bb - 3136) * 256 + t; }
  else if (bb < 3408) { src = Wk;  dhi = Wkv; dlo = nullptr;
                        i = (bb - 3152) * 256 + t; }
  else if (bb < 3664) { src = Wv;  dhi = Wkv + (long)256 * 1024; dlo = nullptr;
                        i = (bb - 3408) * 256 + t; }
  else                { src = Wo;  dhi = Wo_bf2; dlo = nullptr;
                        i = (bb - 3664) * 256 + t; }
  float4 v = *(const float4*)(src + (long)i * 4);
  short4 hv;
  short h0 = f2bf_bits(v.x), h1 = f2bf_bits(v.y);
  short h2 = f2bf_bits(v.z), h3 = f2bf_bits(v.w);
  hv.x = h0; hv.y = h1; hv.z = h2; hv.w = h3;
  *(short4*)&dhi[(long)i * 4] = hv;
  if (dlo) {
    short4 lv;
    lv.x = f2bf_bits(v.x - bf2f(h0)); lv.y = f2bf_bits(v.y - bf2f(h1));
    lv.z = f2bf_bits(v.z - bf2f(h2)); lv.w = f2bf_bits(v.w - bf2f(h3));
    *(short4*)&dlo[(long)i * 4] = lv;
  }
}

// ---- fused projection GEMM: BM=64, BN=64, grid (26, 32); XCD swizzle -------
__global__ __launch_bounds__(256) void gemm_all(
    const short* __restrict__ A_cat, const short* __restrict__ Wh,
    const short* __restrict__ Wl, const short* __restrict__ Wkv,
    const float* __restrict__ bq, const float* __restrict__ bik,
    const float* __restrict__ biw, const float* __restrict__ bk,
    const float* __restrict__ bv, float* __restrict__ qb,
    float* __restrict__ ikb, float* __restrict__ wb, float* __restrict__ kb,
    float* __restrict__ vb) {
  __shared__ short Als[64 * 64] __attribute__((aligned(16)));
  __shared__ short Bls[64 * 64] __attribute__((aligned(16)));
  int flat = blockIdx.x + blockIdx.y * 26;
  int id2 = (flat & 7) * 104 + (flat >> 3);
  int bx = id2 % 26;
  int m0 = (id2 / 26) * 64;
  bool sens = bx < 18;
  int n0 = (sens ? bx : bx - 18) * 64;
  int Nrows = sens ? 1104 : 512;
  int nterm = sens ? 3 : 1;
  int tid = threadIdx.x;
  int lane = tid & 63, wid = tid >> 6;
  int wm = (wid >> 1) * 32, wn = (wid & 1) * 32;   // wave: 32x32 output
  int lr = lane & 15, kg = lane >> 4;
  int arow = tid >> 2, aseg4 = tid & 3;
  int abase = arow * 64 + aseg4 * 16;
  int aswz = (arow & 7) * 8;
  bool bok = (n0 + arow) < Nrows;

  f32x4 acc[2][2] = {};
  for (int term = 0; term < nterm; ++term) {
    const short* Ab = A_cat + (term == 1 ? 1024 : 0);
    const short* Bb = sens ? (term == 2 ? Wl : Wh) : Wkv;
    const short* aseg = Ab + (long)(m0 + arow) * 2048 + aseg4 * 16;
    const short* bseg = Bb + (long)(n0 + arow) * 1024 + aseg4 * 16;
    short8 a0, a1, b0, b1;
    a0 = *(const short8*)(aseg);
    a1 = *(const short8*)(aseg + 8);
    b0 = bok ? *(const short8*)(bseg) : short8{};
    b1 = bok ? *(const short8*)(bseg + 8) : short8{};
    for (int t = 0; t < 16; ++t) {
      __syncthreads();
      *(short8*)&Als[abase ^ aswz] = a0;
      *(short8*)&Als[(abase + 8) ^ aswz] = a1;
      *(short8*)&Bls[abase ^ aswz] = b0;
      *(short8*)&Bls[(abase + 8) ^ aswz] = b1;
      __syncthreads();
      if (t + 1 < 16) {
        const short* an = aseg + (t + 1) * 64;
        const short* bn = bseg + (t + 1) * 64;
        a0 = *(const short8*)(an);
        a1 = *(const short8*)(an + 8);
        b0 = bok ? *(const short8*)(bn) : short8{};
        b1 = bok ? *(const short8*)(bn + 8) : short8{};
      }
#pragma unroll
      for (int kk = 0; kk < 2; ++kk) {
        short8 af[2], bf[2];
#pragma unroll
        for (int f = 0; f < 2; ++f) {
          int ar = wm + f * 16 + lr;
          af[f] = *(short8*)&Als[(ar * 64 + kk * 32 + kg * 8) ^ ((ar & 7) * 8)];
          int br = wn + f * 16 + lr;
          bf[f] = *(short8*)&Bls[(br * 64 + kk * 32 + kg * 8) ^ ((br & 7) * 8)];
        }
#pragma unroll
        for (int fi = 0; fi < 2; ++fi)
#pragma unroll
          for (int fj = 0; fj < 2; ++fj)
            acc[fi][fj] = __builtin_amdgcn_mfma_f32_16x16x32_bf16(
                af[fi], bf[fj], acc[fi][fj], 0, 0, 0);
      }
    }
  }
  int rg = lane >> 4;
#pragma unroll
  for (int fi = 0; fi < 2; ++fi)
#pragma unroll
    for (int fj = 0; fj < 2; ++fj)
#pragma unroll
      for (int r = 0; r < 4; ++r) {
        int gm = m0 + wm + fi * 16 + rg * 4 + r;
        int gn = n0 + wn + fj * 16 + lr;
        float v = acc[fi][fj][r];
        if (sens) {
          if (gn < 1024)      qb[(long)gm * 1024 + gn] = v + bq[gn];
          else if (gn < 1088) ikb[(long)gm * 64 + gn - 1024] = v + bik[gn - 1024];
          else if (gn < 1104) wb[(long)gm * 16 + gn - 1088] = v + biw[gn - 1088];
        } else {
          if (gn < 256) kb[(long)gm * 256 + gn] = v + bk[gn];
          else          vb[(long)gm * 256 + gn - 256] = v + bv[gn - 256];
        }
      }
}

// ---- Wo bf16 GEMM: BM=64, BN=64, grid (16, 32); XCD swizzle ----------------
__global__ __launch_bounds__(256) void gemm_wo(
    const short* __restrict__ A, const short* __restrict__ Bm,
    float* __restrict__ out) {
  __shared__ short Als[64 * 64] __attribute__((aligned(16)));
  __shared__ short Bls[64 * 64] __attribute__((aligned(16)));
  int flat = blockIdx.x + blockIdx.y * 16;   // 512 blocks = 8 XCD x 64
  int id2 = (flat & 7) * 64 + (flat >> 3);
  int n0 = (id2 % 16) * 64;
  int m0 = (id2 / 16) * 64;
  int tid = threadIdx.x;
  int lane = tid & 63, wid = tid >> 6;
  int wm = (wid >> 1) * 32, wn = (wid & 1) * 32;
  int lr = lane & 15, kg = lane >> 4;
  int arow = tid >> 2, aseg4 = tid & 3;
  int abase = arow * 64 + aseg4 * 16;
  int aswz = (arow & 7) * 8;
  const short* aseg = A + (long)(m0 + arow) * 1024 + aseg4 * 16;
  const short* bseg = Bm + (long)(n0 + arow) * 1024 + aseg4 * 16;
  f32x4 acc[2][2] = {};
  short8 a0, a1, b0, b1;
  a0 = *(const short8*)(aseg);
  a1 = *(const short8*)(aseg + 8);
  b0 = *(const short8*)(bseg);
  b1 = *(const short8*)(bseg + 8);
  for (int t = 0; t < 16; ++t) {
    __syncthreads();
    *(short8*)&Als[abase ^ aswz] = a0;
    *(short8*)&Als[(abase + 8) ^ aswz] = a1;
    *(short8*)&Bls[abase ^ aswz] = b0;
    *(short8*)&Bls[(abase + 8) ^ aswz] = b1;
    __syncthreads();
    if (t + 1 < 16) {
      const short* an = aseg + (t + 1) * 64;
      const short* bn = bseg + (t + 1) * 64;
      a0 = *(const short8*)(an);
      a1 = *(const short8*)(an + 8);
      b0 = *(const short8*)(bn);
      b1 = *(const short8*)(bn + 8);
    }
#pragma unroll
    for (int kk = 0; kk < 2; ++kk) {
      short8 af[2], bf[2];
#pragma unroll
      for (int f = 0; f < 2; ++f) {
        int ar = wm + f * 16 + lr;
        af[f] = *(short8*)&Als[(ar * 64 + kk * 32 + kg * 8) ^ ((ar & 7) * 8)];
        int br = wn + f * 16 + lr;
        bf[f] = *(short8*)&Bls[(br * 64 + kk * 32 + kg * 8) ^ ((br & 7) * 8)];
      }
#pragma unroll
      for (int fi = 0; fi < 2; ++fi)
#pragma unroll
        for (int fj = 0; fj < 2; ++fj)
          acc[fi][fj] = __builtin_amdgcn_mfma_f32_16x16x32_bf16(
              af[fi], bf[fj], acc[fi][fj], 0, 0, 0);
    }
  }
  int rg = lane >> 4;
#pragma unroll
  for (int fi = 0; fi < 2; ++fi)
#pragma unroll
    for (int fj = 0; fj < 2; ++fj)
#pragma unroll
      for (int r = 0; r < 4; ++r) {
        int gm = m0 + wm + fi * 16 + rg * 4 + r;
        int gn = n0 + wn + fj * 16 + lr;
        out[(long)gm * 1024 + gn] = acc[fi][fj][r];
      }
}

// ---- RoPE + fused 3-way splits (q,ik) + bf16 K copy ------------------------
__global__ void rope_kernel(float* __restrict__ q, float* __restrict__ k,
                            float* __restrict__ ik, short* __restrict__ k_bf,
                            short* __restrict__ qh, short* __restrict__ qm,
                            short* __restrict__ ql, short* __restrict__ ikh,
                            short* __restrict__ ikm, short* __restrict__ ikl,
                            int big,
                            const float* __restrict__ cosb,
                            const float* __restrict__ sinb) {
  int gid = blockIdx.x * 256 + threadIdx.x;
  const int NV = SEQ * (NH + NKV + 1);
  if (gid >= NV * 32) return;
  int p = gid & 31;
  int vec = gid >> 5;
  int s;
  if (vec < SEQ * NH) {                     // q branch
    s = vec / NH; int h = vec % NH;
    long off = (long)s * 1024 + h * 64;
    float c = cosb[s * 64 + p], sn = sinb[s * 64 + p];
    float x1 = q[off + p], x2 = q[off + p + 32];
    float y1 = x1 * c - x2 * sn;
    float y2 = x2 * c + x1 * sn;
    q[off + p] = y1;
    q[off + p + 32] = y2;
    if (big) {
      short h1, m1, l1, h2, m2, l2;
      split3(y1, h1, m1, l1);
      split3(y2, h2, m2, l2);
      qh[off + p] = h1; qm[off + p] = m1; ql[off + p] = l1;
      qh[off + p + 32] = h2; qm[off + p + 32] = m2; ql[off + p + 32] = l2;
    }
  } else if (vec < SEQ * (NH + NKV)) {      // k branch (+ bf16 copy)
    int t = vec - SEQ * NH;
    s = t / NKV; int kh = t % NKV;
    long off = (long)s * 256 + kh * 64;
    float c = cosb[s * 64 + p], sn = sinb[s * 64 + p];
    float x1 = k[off + p], x2 = k[off + p + 32];
    float y1 = x1 * c - x2 * sn;
    float y2 = x2 * c + x1 * sn;
    k[off + p] = y1;
    k[off + p + 32] = y2;
    k_bf[off + p] = f2bf_bits(y1);
    k_bf[off + p + 32] = f2bf_bits(y2);
  } else {                                  // ik branch (+ splits)
    s = vec - SEQ * (NH + NKV);
    long off = (long)s * 64;
    float c = cosb[s * 64 + p], sn = sinb[s * 64 + p];
    float x1 = ik[off + p], x2 = ik[off + p + 32];
    float y1 = x1 * c - x2 * sn;
    float y2 = x2 * c + x1 * sn;
    ik[off + p] = y1;
    ik[off + p + 32] = y2;
    if (big) {
      short h1, m1, l1, h2, m2, l2;
      split3(y1, h1, m1, l1);
      split3(y2, h2, m2, l2);
      ikh[off + p] = h1; ikm[off + p] = m1; ikl[off + p] = l1;
      ikh[off + p + 32] = h2; ikm[off + p + 32] = m2; ikl[off + p + 32] = l2;
    }
  }
}

// ---- MFMA indexer scores, EXACT 3-way split; next-h q prefetched to regs ---
__global__ __launch_bounds__(256) void idx_mfma6(
    const short* __restrict__ q_h, const short* __restrict__ q_m,
    const short* __restrict__ q_l, const short* __restrict__ ik_h,
    const short* __restrict__ ik_m, const short* __restrict__ ik_l,
    const float* __restrict__ wb, float* __restrict__ sc) {
  int b = blockIdx.x;                         // 0..527 triangular
  int tq = (int)((sqrtf(8.f * b + 1.f) - 1.f) * 0.5f);
  while ((tq * (tq + 1)) / 2 > b) --tq;
  while (((tq + 1) * (tq + 2)) / 2 <= b) ++tq;
  int tk = b - (tq * (tq + 1)) / 2;
  int q0 = tq * 64, k0 = tk * 64;

  __shared__ short QH[64 * 64] __attribute__((aligned(16)));
  __shared__ short QM[64 * 64] __attribute__((aligned(16)));
  __shared__ short QL[64 * 64] __attribute__((aligned(16)));
  __shared__ short IH[64 * 64] __attribute__((aligned(16)));
  __shared__ short IM[64 * 64] __attribute__((aligned(16)));
  __shared__ short IL[64 * 64] __attribute__((aligned(16)));
  __shared__ float wls[64][17];

  int tid = threadIdx.x;
  int lane = tid & 63, wid = tid >> 6;
  int wm = (wid >> 1) * 32, wn = (wid & 1) * 32;
  int lr = lane & 15, kg = lane >> 4;
  int sr = tid >> 2, seg = tid & 3;
  int sbase = sr * 64 + seg * 16;
  int sswz = (sr & 7) * 8;

  {  // stage ik tiles (once) + w tile
    const short* g0 = ik_h + (long)(k0 + sr) * 64 + seg * 16;
    const short* g1 = ik_m + (long)(k0 + sr) * 64 + seg * 16;
    const short* g2 = ik_l + (long)(k0 + sr) * 64 + seg * 16;
#pragma unroll
    for (int c = 0; c < 2; ++c) {
      *(short8*)&IH[(sbase + c * 8) ^ sswz] = *(const short8*)(g0 + c * 8);
      *(short8*)&IM[(sbase + c * 8) ^ sswz] = *(const short8*)(g1 + c * 8);
      *(short8*)&IL[(sbase + c * 8) ^ sswz] = *(const short8*)(g2 + c * 8);
    }
    int wlc = tid & 15, wlr = tid >> 4;
#pragma unroll
    for (int i = 0; i < 4; ++i)
      wls[wlr + 16 * i][wlc] = wb[(long)(q0 + wlr + 16 * i) * 16 + wlc] * 0.25f;
  }
  long qrow = (long)(q0 + sr) * 1024 + seg * 16;
  short8 pa0 = *(const short8*)(q_h + qrow);
  short8 pa1 = *(const short8*)(q_h + qrow + 8);
  short8 pb0 = *(const short8*)(q_m + qrow);
  short8 pb1 = *(const short8*)(q_m + qrow + 8);
  short8 pc0 = *(const short8*)(q_l + qrow);
  short8 pc1 = *(const short8*)(q_l + qrow + 8);
  __syncthreads();
  short8 bh[2][2], bm_[2][2], bl_[2][2];
#pragma unroll
  for (int fj = 0; fj < 2; ++fj)
#pragma unroll
    for (int ks = 0; ks < 2; ++ks) {
      int br = wn + fj * 16 + lr;
      int idx = (br * 64 + ks * 32 + kg * 8) ^ ((br & 7) * 8);
      bh[fj][ks] = *(short8*)&IH[idx];
      bm_[fj][ks] = *(short8*)&IM[idx];
      bl_[fj][ks] = *(short8*)&IL[idx];
    }

  int rg = lane >> 4;
  f32x4 acc[2][2] = {};
  for (int h = 0; h < NH; ++h) {
    __syncthreads();                       // prior h's A-frag reads done
    *(short8*)&QH[sbase ^ sswz] = pa0;
    *(short8*)&QH[(sbase + 8) ^ sswz] = pa1;
    *(short8*)&QM[sbase ^ sswz] = pb0;
    *(short8*)&QM[(sbase + 8) ^ sswz] = pb1;
    *(short8*)&QL[sbase ^ sswz] = pc0;
    *(short8*)&QL[(sbase + 8) ^ sswz] = pc1;
    if (h + 1 < NH) {                      // prefetch next h (hidden by MFMA)
      long nrow = qrow + (h + 1) * 64;
      pa0 = *(const short8*)(q_h + nrow);
      pa1 = *(const short8*)(q_h + nrow + 8);
      pb0 = *(const short8*)(q_m + nrow);
      pb1 = *(const short8*)(q_m + nrow + 8);
      pc0 = *(const short8*)(q_l + nrow);
      pc1 = *(const short8*)(q_l + nrow + 8);
    }
    __syncthreads();
    f32x4 dot[2][2] = {};
#pragma unroll
    for (int ks = 0; ks < 2; ++ks) {
      short8 ah[2], am[2], al[2];
#pragma unroll
      for (int fi = 0; fi < 2; ++fi) {
        int ar = wm + fi * 16 + lr;
        int idx = (ar * 64 + ks * 32 + kg * 8) ^ ((ar & 7) * 8);
        ah[fi] = *(short8*)&QH[idx];
        am[fi] = *(short8*)&QM[idx];
        al[fi] = *(short8*)&QL[idx];
      }
#pragma unroll
      for (int fi = 0; fi < 2; ++fi)
#pragma unroll
        for (int fj = 0; fj < 2; ++fj) {
          dot[fi][fj] = __builtin_amdgcn_mfma_f32_16x16x32_bf16(
              ah[fi], bh[fj][ks], dot[fi][fj], 0, 0, 0);      // hh
          dot[fi][fj] = __builtin_amdgcn_mfma_f32_16x16x32_bf16(
              ah[fi], bm_[fj][ks], dot[fi][fj], 0, 0, 0);     // hm
          dot[fi][fj] = __builtin_amdgcn_mfma_f32_16x16x32_bf16(
              am[fi], bh[fj][ks], dot[fi][fj], 0, 0, 0);      // mh
          dot[fi][fj] = __builtin_amdgcn_mfma_f32_16x16x32_bf16(
              ah[fi], bl_[fj][ks], dot[fi][fj], 0, 0, 0);     // hl
          dot[fi][fj] = __builtin_amdgcn_mfma_f32_16x16x32_bf16(
              am[fi], bm_[fj][ks], dot[fi][fj], 0, 0, 0);     // mm
          dot[fi][fj] = __builtin_amdgcn_mfma_f32_16x16x32_bf16(
              al[fi], bh[fj][ks], dot[fi][fj], 0, 0, 0);      // lh
        }
    }
#pragma unroll
    for (int fi = 0; fi < 2; ++fi) {
      float wv[4];
#pragma unroll
      for (int r = 0; r < 4; ++r) wv[r] = wls[wm + fi * 16 + rg * 4 + r][h];
#pragma unroll
      for (int fj = 0; fj < 2; ++fj)
#pragma unroll
        for (int r = 0; r < 4; ++r)
          acc[fi][fj][r] += fmaxf(dot[fi][fj][r], 0.f) * wv[r];
    }
  }
#pragma unroll
  for (int fi = 0; fi < 2; ++fi)
#pragma unroll
    for (int fj = 0; fj < 2; ++fj)
#pragma unroll
      for (int r = 0; r < 4; ++r) {
        int q = q0 + wm + fi * 16 + rg * 4 + r;
        int k = k0 + wn + fj * 16 + lr;
        if (k <= q) sc[(long)q * (q + 1) / 2 + k] = acc[fi][fj][r];
      }
}

// ---- fallback VALU indexer (if ws too small for splits) --------------------
__global__ __launch_bounds__(256) void idx_scores(
    const float* __restrict__ qb, const float* __restrict__ ikb,
    const float* __restrict__ wb, float* __restrict__ sc) {
  int b = blockIdx.x;
  int tq = (int)((sqrtf(8.f * b + 1.f) - 1.f) * 0.5f);
  while ((tq * (tq + 1)) / 2 > b) --tq;
  while (((tq + 1) * (tq + 2)) / 2 <= b) ++tq;
  int tk = b - (tq * (tq + 1)) / 2;
  int q0 = tq * 64, k0 = tk * 64;
  __shared__ float As0[64][68];
  __shared__ float As1[64][68];
  __shared__ float Bs[64][68];
  __shared__ float wls[64][17];
  int tid = threadIdx.x;
  int lc = tid & 15, lr = tid >> 4;
  int tx = lc, ty = lr;
#pragma unroll
  for (int c = 0; c < 4; ++c) {
    int d = c * 16 + lc;
#pragma unroll
    for (int i = 0; i < 4; ++i)
      Bs[d][lr + 16 * i] = ikb[(long)(k0 + lr + 16 * i) * 64 + d];
  }
#pragma unroll
  for (int i = 0; i < 4; ++i)
    wls[lr + 16 * i][lc] = wb[(long)(q0 + lr + 16 * i) * 16 + lc] * 0.25f;
  float pf0[16], pf1[16];
#pragma unroll
  for (int c = 0; c < 4; ++c)
#pragma unroll
    for (int i = 0; i < 4; ++i) {
      long base = (long)(q0 + lr + 16 * i) * 1024 + c * 16 + lc;
      pf0[c * 4 + i] = qb[base];
      pf1[c * 4 + i] = qb[base + 64];
    }
  float acc[4][4] = {};
  for (int hp = 0; hp < 8; ++hp) {
    __syncthreads();
#pragma unroll
    for (int c = 0; c < 4; ++c)
#pragma unroll
      for (int i = 0; i < 4; ++i) {
        As0[c * 16 + lc][lr + 16 * i] = pf0[c * 4 + i];
        As1[c * 16 + lc][lr + 16 * i] = pf1[c * 4 + i];
      }
    if (hp < 7) {
#pragma unroll
      for (int c = 0; c < 4; ++c)
#pragma unroll
        for (int i = 0; i < 4; ++i) {
          long base =
              (long)(q0 + lr + 16 * i) * 1024 + (2 * hp + 2) * 64 + c * 16 + lc;
          pf0[c * 4 + i] = qb[base];
          pf1[c * 4 + i] = qb[base + 64];
        }
    }
    __syncthreads();
    float wv0[4], wv1[4];
#pragma unroll
    for (int i = 0; i < 4; ++i) {
      wv0[i] = wls[ty * 4 + i][2 * hp];
      wv1[i] = wls[ty * 4 + i][2 * hp + 1];
    }
    float dot0[4][4] = {}, dot1[4][4] = {};
#pragma unroll
    for (int kk = 0; kk < 64; ++kk) {
      float4 a0 = *(const float4*)&As0[kk][ty * 4];
      float4 a1 = *(const float4*)&As1[kk][ty * 4];
      float4 b4 = *(const float4*)&Bs[kk][tx * 4];
      float av0[4] = {a0.x, a0.y, a0.z, a0.w};
      float av1[4] = {a1.x, a1.y, a1.z, a1.w};
      float bv[4] = {b4.x, b4.y, b4.z, b4.w};
#pragma unroll
      for (int i = 0; i < 4; ++i)
#pragma unroll
        for (int j = 0; j < 4; ++j) {
          dot0[i][j] += av0[i] * bv[j];
          dot1[i][j] += av1[i] * bv[j];
        }
    }
#pragma unroll
    for (int i = 0; i < 4; ++i)
#pragma unroll
      for (int j = 0; j < 4; ++j) {
        acc[i][j] += fmaxf(dot0[i][j], 0.f) * wv0[i];
        acc[i][j] += fmaxf(dot1[i][j], 0.f) * wv1[i];
      }
  }
#pragma unroll
  for (int i = 0; i < 4; ++i) {
    int q = q0 + ty * 4 + i;
    long base = (long)q * (q + 1) / 2;
#pragma unroll
    for (int j = 0; j < 4; ++j) {
      int k = k0 + tx * 4 + j;
      if (k <= q) sc[base + k] = acc[i][j];
    }
  }
}

// ---- exact top-128 per row, one wave per row -------------------------------
__device__ inline unsigned fkey(float f) {
  unsigned u = __float_as_uint(f);
  return (u & 0x80000000u) ? ~u : (u | 0x80000000u);
}

__global__ __launch_bounds__(64) void topk_rows(
    const float* __restrict__ sc, int* __restrict__ tidx,
    int* __restrict__ tcnt) {
  int qi = blockIdx.x;
  int lane = threadIdx.x;
  if (qi < TOPK) {
    for (int i = lane; i <= qi; i += 64) tidx[(long)qi * TOPK + i] = i;
    if (lane == 0) tcnt[qi] = qi + 1;
    return;
  }
  const float* row = sc + (long)qi * (qi + 1) / 2;
  unsigned keys[32];
#pragma unroll
  for (int i = 0; i < 32; ++i) {
    int k = lane + 64 * i;
    keys[i] = (k <= qi) ? fkey(row[k] + 0.f) : 0u;
  }
  unsigned lo = 0u, hi = 0xFFFFFFFEu;
  while (lo < hi) {
    unsigned mid = lo + ((hi - lo + 1) >> 1);
    int cnt = 0;
#pragma unroll
    for (int i = 0; i < 32; ++i) cnt += (keys[i] >= mid) ? 1 : 0;
    for (int off = 32; off; off >>= 1) cnt += __shfl_xor(cnt, off);
    if (cnt >= TOPK) lo = mid; else hi = mid - 1;
  }
  unsigned T = lo;
  __shared__ int c1;
  if (lane == 0) c1 = 0;
  __syncthreads();
#pragma unroll
  for (int i = 0; i < 32; ++i) {
    if (keys[i] > T) {
      int pos = atomicAdd(&c1, 1);
      tidx[(long)qi * TOPK + pos] = lane + 64 * i;
    }
  }
  __syncthreads();
  int c = c1;
  for (int i = 0; i < 32 && c < TOPK; ++i) {
    unsigned long long m = __ballot(keys[i] == T);
    while (m && c < TOPK) {
      int l = __ffsll(m) - 1;
      m &= m - 1;
      if (lane == 0) tidx[(long)qi * TOPK + c] = 64 * i + l;
      ++c;
    }
  }
  if (lane == 0) tcnt[qi] = TOPK;
}

// ---- sparse attention: block (q, kvh); 4 waves; K staged as bf16 in LDS ----
__global__ __launch_bounds__(256) void sparse_attn(
    const float* __restrict__ qb, const short* __restrict__ kb_bf,
    const float* __restrict__ vb, const int* __restrict__ tidx,
    const int* __restrict__ tcnt, short* __restrict__ attn) {
  int kvh = blockIdx.x;
  int qi  = blockIdx.y;
  int tid = threadIdx.x, lane = tid & 63, w = tid >> 6;
  int h = kvh * 4 + w;
  int cnt = tcnt[qi];
  __shared__ int   idxs[128];
  __shared__ short Ks[128][68] __attribute__((aligned(16)));
  __shared__ float qs[4][64];
  __shared__ float ps[4][128];
  if (tid < 128) idxs[tid] = (tid < cnt) ? tidx[(long)qi * TOPK + tid] : 0;
  qs[w][lane] = qb[(long)qi * 1024 + h * 64 + lane];
  __syncthreads();
  {
    int j0 = tid >> 2, qf = tid & 3;     // 4 threads per K row (coalesced)
#pragma unroll
    for (int pass = 0; pass < 2; ++pass) {
      int j = j0 + pass * 64;
      if (j < cnt) {
        int ki = idxs[j];
        const short* kr = kb_bf + (long)ki * 256 + kvh * 64 + qf * 16;
        short8 k0 = *(const short8*)(kr);
        short8 k1 = *(const short8*)(kr + 8);
        *(short4*)&Ks[j][qf * 16 + 0]  = *(short4*)&k0;
        *(short4*)&Ks[j][qf * 16 + 4]  = *((short4*)&k0 + 1);
        *(short4*)&Ks[j][qf * 16 + 8]  = *(short4*)&k1;
        *(short4*)&Ks[j][qf * 16 + 12] = *((short4*)&k1 + 1);
      }
    }
  }
  __syncthreads();
  float4 qreg[16];
#pragma unroll
  for (int c = 0; c < 16; ++c) qreg[c] = *(const float4*)&qs[w][c * 4];
  float l0 = -INFINITY, l1 = -INFINITY;
#pragma unroll
  for (int slot = 0; slot < 2; ++slot) {
    int j = lane + slot * 64;
    if (j < cnt) {
      float d = 0.f;
#pragma unroll
      for (int c = 0; c < 16; ++c) {
        short4 kk4 = *(const short4*)&Ks[j][c * 4];
        d += qreg[c].x * bf2f(kk4.x);
        d += qreg[c].y * bf2f(kk4.y);
        d += qreg[c].z * bf2f(kk4.z);
        d += qreg[c].w * bf2f(kk4.w);
      }
      float l = d * 0.125f;
      if (slot == 0) l0 = l; else l1 = l;
    }
  }
  float m = fmaxf(l0, l1);
  for (int off = 32; off; off >>= 1) m = fmaxf(m, __shfl_xor(m, off));
  float p0 = expf(l0 - m), p1 = expf(l1 - m);
  float ssum = p0 + p1;
  for (int off = 32; off; off >>= 1) ssum += __shfl_xor(ssum, off);
  ps[w][lane] = p0;
  ps[w][lane + 64] = p1;
  __syncthreads();
  int sub = lane >> 4, quad = lane & 15;
  float4 o4 = {0.f, 0.f, 0.f, 0.f};
#pragma unroll 4
  for (int j = sub; j < cnt; j += 4) {
    int ki = idxs[j];
    float p = ps[w][j];
    float4 vv = *(const float4*)(vb + (long)ki * 256 + kvh * 64 + quad * 4);
    o4.x += p * vv.x; o4.y += p * vv.y;
    o4.z += p * vv.z; o4.w += p * vv.w;
  }
#pragma unroll
  for (int off = 16; off <= 32; off <<= 1) {
    o4.x += __shfl_xor(o4.x, off);
    o4.y += __shfl_xor(o4.y, off);
    o4.z += __shfl_xor(o4.z, off);
    o4.w += __shfl_xor(o4.w, off);
  }
  if (sub == 0) {
    float inv = 1.f / ssum;
    short4 ov;
    ov.x = f2bf_bits(o4.x * inv); ov.y = f2bf_bits(o4.y * inv);
    ov.z = f2bf_bits(o4.z * inv); ov.w = f2bf_bits(o4.w * inv);
    *(short4*)&attn[(long)qi * 1024 + h * 64 + quad * 4] = ov;
  }
}

// ---- f32 -> bf16 (hi only), fallback path for Wo ---------------------------
__global__ __launch_bounds__(256) void conv_hi(
    const float* __restrict__ src, short* __restrict__ dst, int n4) {
  int i = blockIdx.x * 256 + threadIdx.x;
  if (i >= n4) return;
  float4 v = *(const float4*)(src + (long)i * 4);
  short4 hv;
  hv.x = f2bf_bits(v.x); hv.y = f2bf_bits(v.y);
  hv.z = f2bf_bits(v.z); hv.w = f2bf_bits(v.w);
  *(short4*)&dst[(long)i * 4] = hv;
}

// ---------------------------------------------------------------------------
extern "C" void kernel_launch(void* const* d_in, const int* in_sizes, int n_in,
                              void* d_out, int out_size, void* d_ws,
                              size_t ws_size, hipStream_t stream) {
  const float* hs   = (const float*)d_in[0];
  const float* cosb = (const float*)d_in[1];
  const float* sinb = (const float*)d_in[2];
  const float* Wq   = (const float*)d_in[3];
  const float* bq   = (const float*)d_in[4];
  const float* Wk   = (const float*)d_in[5];
  const float* bk   = (const float*)d_in[6];
  const float* Wv   = (const float*)d_in[7];
  const float* bv   = (const float*)d_in[8];
  const float* Wo   = (const float*)d_in[9];
  const float* Wik  = (const float*)d_in[10];
  const float* bik  = (const float*)d_in[11];
  const float* Wiw  = (const float*)d_in[12];
  const float* biw  = (const float*)d_in[13];
  float* out = (float*)d_out;

  float* ws = (float*)d_ws;
  float* qb   = ws;  ws += (long)SEQ * 1024;
  float* kb   = ws;  ws += (long)SEQ * 256;
  float* vb   = ws;  ws += (long)SEQ * 256;
  float* ikb  = ws;  ws += (long)SEQ * 64;
  float* wb   = ws;  ws += (long)SEQ * 16;
  int* tidx   = (int*)ws;  ws += (long)SEQ * TOPK;
  int* tcnt   = (int*)ws;  ws += SEQ;
  short* kb_bf = (short*)ws; ws += (long)SEQ * 128;   // S x 256 bf16 = 1 MB
  float* R1   = ws;  ws += (long)SEQ * (SEQ + 1) / 2;
  float* R2   = ws;  ws += (long)1104 * 1024;
  float* R3   = ws;  ws += 3L * SEQ * 512;            // q_h/m/l splits
  float* R4   = ws;  ws += (long)512 * 1024;          // Wo_bf2: 1024x1024 bf16
  size_t need_big = (size_t)(ws - (float*)d_ws) * 4;  // ~42.8 MB
  int big = ws_size >= need_big;

  short* A_cat   = (short*)R1;          // 8 MB (dead before scores)
  float* scores  = R1;
  short* Wh      = (short*)R2;
  short* Wl      = Wh + (long)1104 * 1024;
  short* attn_bf = (short*)R2;          // Wh/Wl dead by then
  short* Wkv_bf  = (short*)tidx;        // dead before tidx written
  short* Wo_bf2  = (short*)R4;          // dedicated (big path)
  short* Wo_bf_s = (short*)qb;          // fallback alias (small path)
  short* q_h     = (short*)R3;          // 4 MB each
  short* q_m     = q_h + (long)SEQ * 1024;
  short* q_l     = q_m + (long)SEQ * 1024;
  short* ik_h    = (short*)tidx;        // 3 x 256KB <= 1MB
  short* ik_m    = ik_h + (long)SEQ * 64;
  short* ik_l    = ik_m + (long)SEQ * 64;

  dim3 blk(256);
  // big path: convert Wo up-front inside conv_all (removes a tail dispatch)
  int conv_blocks = big ? 4688 : 3664;
  conv_all<<<conv_blocks, blk, 0, stream>>>(hs, Wq, Wik, Wiw, Wk, Wv, Wo,
                                            A_cat, Wh, Wl, Wkv_bf, Wo_bf2);
  gemm_all<<<dim3(26, 32), blk, 0, stream>>>(A_cat, Wh, Wl, Wkv_bf, bq, bik,
                                             biw, bk, bv, qb, ikb, wb, kb, vb);

  int nrope = SEQ * (NH + NKV + 1) * 32;
  rope_kernel<<<(nrope + 255) / 256, blk, 0, stream>>>(
      qb, kb, ikb, kb_bf, q_h, q_m, q_l, ik_h, ik_m, ik_l, big, cosb, sinb);

  if (big) {
    idx_mfma6<<<528, blk, 0, stream>>>(q_h, q_m, q_l, ik_h, ik_m, ik_l, wb,
                                       scores);
  } else {
    idx_scores<<<528, blk, 0, stream>>>(qb, ikb, wb, scores);
  }
  topk_rows<<<SEQ, dim3(64), 0, stream>>>(scores, tidx, tcnt);

  sparse_attn<<<dim3(NKV, SEQ), blk, 0, stream>>>(qb, kb_bf, vb, tidx, tcnt,
                                                  attn_bf);

  if (big) {
    gemm_wo<<<dim3(16, 32), blk, 0, stream>>>(attn_bf, Wo_bf2, out);
  } else {
    conv_hi<<<1024, blk, 0, stream>>>(Wo, Wo_bf_s, 1024 * 256);
    gemm_wo<<<dim3(16, 32), blk, 0, stream>>>(attn_bf, Wo_bf_s, out);
  }
}

// Round 30
// 178.134 us; speedup vs baseline: 1.2940x; 1.0289x over previous
//
#include <hip/hip_runtime.h>
#include <hip/hip_bf16.h>
#include <math.h>

#define SEQ   2048
#define HDIM  1024
#define NH    16
#define NKV   4
#define DHEAD 64
#define TOPK  128

typedef __attribute__((ext_vector_type(8))) short short8;
typedef __attribute__((ext_vector_type(4))) float f32x4;

__device__ inline short f2bf_bits(float x) {          // RTN-even f32 -> bf16
  unsigned u = __float_as_uint(x);
  unsigned r = (u + 0x7FFFu + ((u >> 16) & 1u)) >> 16;
  return (short)r;
}
__device__ inline float bf2f(short s) {
  return __uint_as_float(((unsigned)(unsigned short)s) << 16);
}
__device__ inline void split3(float x, short& h, short& m, short& l) {
  h = f2bf_bits(x);
  float r1 = x - bf2f(h);
  m = f2bf_bits(r1);
  l = f2bf_bits(r1 - bf2f(m));
}

// ---- fused conversions: one dispatch, segmented grid -----------------------
// seg5 end extended: [3664, 4688) converts Wo -> Wo_bf2 (big path only).
__global__ __launch_bounds__(256) void conv_all(
    const float* __restrict__ hs, const float* __restrict__ Wq,
    const float* __restrict__ Wik, const float* __restrict__ Wiw,
    const float* __restrict__ Wk, const float* __restrict__ Wv,
    const float* __restrict__ Wo,
    short* __restrict__ A_cat, short* __restrict__ Wh, short* __restrict__ Wl,
    short* __restrict__ Wkv, short* __restrict__ Wo_bf2) {
  int bb = blockIdx.x;
  int t = threadIdx.x;
  if (bb < 2048) {                          // hs split -> concat rows
    int i = bb * 256 + t;
    float4 v = *(const float4*)(hs + (long)i * 4);
    int r = i >> 8, c = (i & 255) * 4;
    short4 hv, lv;
    short h0 = f2bf_bits(v.x), h1 = f2bf_bits(v.y);
    short h2 = f2bf_bits(v.z), h3 = f2bf_bits(v.w);
    hv.x = h0; hv.y = h1; hv.z = h2; hv.w = h3;
    lv.x = f2bf_bits(v.x - bf2f(h0)); lv.y = f2bf_bits(v.y - bf2f(h1));
    lv.z = f2bf_bits(v.z - bf2f(h2)); lv.w = f2bf_bits(v.w - bf2f(h3));
    *(short4*)&A_cat[(long)r * 2048 + c] = hv;
    *(short4*)&A_cat[(long)r * 2048 + 1024 + c] = lv;
    return;
  }
  const float* src; short *dhi, *dlo; int i;
  if (bb < 3072)      { src = Wq;  dhi = Wh; dlo = Wl;
                        i = (bb - 2048) * 256 + t; }
  else if (bb < 3136) { src = Wik; dhi = Wh + (long)1024 * 1024;
                        dlo = Wl + (long)1024 * 1024;
                        i = (bb - 3072) * 256 + t; }
  else if (bb < 3152) { src = Wiw; dhi = Wh + (long)1088 * 1024;
                        dlo = Wl + (long)1088 * 1024;
                        i = (bb - 3136) * 256 + t; }
  else if (bb < 3408) { src = Wk;  dhi = Wkv; dlo = nullptr;
                        i = (bb - 3152) * 256 + t; }
  else if (bb < 3664) { src = Wv;  dhi = Wkv + (long)256 * 1024; dlo = nullptr;
                        i = (bb - 3408) * 256 + t; }
  else                { src = Wo;  dhi = Wo_bf2; dlo = nullptr;
                        i = (bb - 3664) * 256 + t; }
  float4 v = *(const float4*)(src + (long)i * 4);
  short4 hv;
  short h0 = f2bf_bits(v.x), h1 = f2bf_bits(v.y);
  short h2 = f2bf_bits(v.z), h3 = f2bf_bits(v.w);
  hv.x = h0; hv.y = h1; hv.z = h2; hv.w = h3;
  *(short4*)&dhi[(long)i * 4] = hv;
  if (dlo) {
    short4 lv;
    lv.x = f2bf_bits(v.x - bf2f(h0)); lv.y = f2bf_bits(v.y - bf2f(h1));
    lv.z = f2bf_bits(v.z - bf2f(h2)); lv.w = f2bf_bits(v.w - bf2f(h3));
    *(short4*)&dlo[(long)i * 4] = lv;
  }
}

// ---- fused projection GEMM: BM=64, BN=64, grid (26, 32); XCD swizzle -------
__global__ __launch_bounds__(256) void gemm_all(
    const short* __restrict__ A_cat, const short* __restrict__ Wh,
    const short* __restrict__ Wl, const short* __restrict__ Wkv,
    const float* __restrict__ bq, const float* __restrict__ bik,
    const float* __restrict__ biw, const float* __restrict__ bk,
    const float* __restrict__ bv, float* __restrict__ qb,
    float* __restrict__ ikb, float* __restrict__ wb, float* __restrict__ kb,
    float* __restrict__ vb) {
  __shared__ short Als[64 * 64] __attribute__((aligned(16)));
  __shared__ short Bls[64 * 64] __attribute__((aligned(16)));
  int flat = blockIdx.x + blockIdx.y * 26;
  int id2 = (flat & 7) * 104 + (flat >> 3);
  int bx = id2 % 26;
  int m0 = (id2 / 26) * 64;
  bool sens = bx < 18;
  int n0 = (sens ? bx : bx - 18) * 64;
  int Nrows = sens ? 1104 : 512;
  int nterm = sens ? 3 : 1;
  int tid = threadIdx.x;
  int lane = tid & 63, wid = tid >> 6;
  int wm = (wid >> 1) * 32, wn = (wid & 1) * 32;   // wave: 32x32 output
  int lr = lane & 15, kg = lane >> 4;
  int arow = tid >> 2, aseg4 = tid & 3;
  int abase = arow * 64 + aseg4 * 16;
  int aswz = (arow & 7) * 8;
  bool bok = (n0 + arow) < Nrows;

  f32x4 acc[2][2] = {};
  for (int term = 0; term < nterm; ++term) {
    const short* Ab = A_cat + (term == 1 ? 1024 : 0);
    const short* Bb = sens ? (term == 2 ? Wl : Wh) : Wkv;
    const short* aseg = Ab + (long)(m0 + arow) * 2048 + aseg4 * 16;
    const short* bseg = Bb + (long)(n0 + arow) * 1024 + aseg4 * 16;
    short8 a0, a1, b0, b1;
    a0 = *(const short8*)(aseg);
    a1 = *(const short8*)(aseg + 8);
    b0 = bok ? *(const short8*)(bseg) : short8{};
    b1 = bok ? *(const short8*)(bseg + 8) : short8{};
    for (int t = 0; t < 16; ++t) {
      __syncthreads();
      *(short8*)&Als[abase ^ aswz] = a0;
      *(short8*)&Als[(abase + 8) ^ aswz] = a1;
      *(short8*)&Bls[abase ^ aswz] = b0;
      *(short8*)&Bls[(abase + 8) ^ aswz] = b1;
      __syncthreads();
      if (t + 1 < 16) {
        const short* an = aseg + (t + 1) * 64;
        const short* bn = bseg + (t + 1) * 64;
        a0 = *(const short8*)(an);
        a1 = *(const short8*)(an + 8);
        b0 = bok ? *(const short8*)(bn) : short8{};
        b1 = bok ? *(const short8*)(bn + 8) : short8{};
      }
#pragma unroll
      for (int kk = 0; kk < 2; ++kk) {
        short8 af[2], bf[2];
#pragma unroll
        for (int f = 0; f < 2; ++f) {
          int ar = wm + f * 16 + lr;
          af[f] = *(short8*)&Als[(ar * 64 + kk * 32 + kg * 8) ^ ((ar & 7) * 8)];
          int br = wn + f * 16 + lr;
          bf[f] = *(short8*)&Bls[(br * 64 + kk * 32 + kg * 8) ^ ((br & 7) * 8)];
        }
#pragma unroll
        for (int fi = 0; fi < 2; ++fi)
#pragma unroll
          for (int fj = 0; fj < 2; ++fj)
            acc[fi][fj] = __builtin_amdgcn_mfma_f32_16x16x32_bf16(
                af[fi], bf[fj], acc[fi][fj], 0, 0, 0);
      }
    }
  }
  int rg = lane >> 4;
#pragma unroll
  for (int fi = 0; fi < 2; ++fi)
#pragma unroll
    for (int fj = 0; fj < 2; ++fj)
#pragma unroll
      for (int r = 0; r < 4; ++r) {
        int gm = m0 + wm + fi * 16 + rg * 4 + r;
        int gn = n0 + wn + fj * 16 + lr;
        float v = acc[fi][fj][r];
        if (sens) {
          if (gn < 1024)      qb[(long)gm * 1024 + gn] = v + bq[gn];
          else if (gn < 1088) ikb[(long)gm * 64 + gn - 1024] = v + bik[gn - 1024];
          else if (gn < 1104) wb[(long)gm * 16 + gn - 1088] = v + biw[gn - 1088];
        } else {
          if (gn < 256) kb[(long)gm * 256 + gn] = v + bk[gn];
          else          vb[(long)gm * 256 + gn - 256] = v + bv[gn - 256];
        }
      }
}

// ---- Wo bf16 GEMM: BM=64, BN=64, grid (16, 32); XCD swizzle ----------------
__global__ __launch_bounds__(256) void gemm_wo(
    const short* __restrict__ A, const short* __restrict__ Bm,
    float* __restrict__ out) {
  __shared__ short Als[64 * 64] __attribute__((aligned(16)));
  __shared__ short Bls[64 * 64] __attribute__((aligned(16)));
  int flat = blockIdx.x + blockIdx.y * 16;   // 512 blocks = 8 XCD x 64
  int id2 = (flat & 7) * 64 + (flat >> 3);
  int n0 = (id2 % 16) * 64;
  int m0 = (id2 / 16) * 64;
  int tid = threadIdx.x;
  int lane = tid & 63, wid = tid >> 6;
  int wm = (wid >> 1) * 32, wn = (wid & 1) * 32;
  int lr = lane & 15, kg = lane >> 4;
  int arow = tid >> 2, aseg4 = tid & 3;
  int abase = arow * 64 + aseg4 * 16;
  int aswz = (arow & 7) * 8;
  const short* aseg = A + (long)(m0 + arow) * 1024 + aseg4 * 16;
  const short* bseg = Bm + (long)(n0 + arow) * 1024 + aseg4 * 16;
  f32x4 acc[2][2] = {};
  short8 a0, a1, b0, b1;
  a0 = *(const short8*)(aseg);
  a1 = *(const short8*)(aseg + 8);
  b0 = *(const short8*)(bseg);
  b1 = *(const short8*)(bseg + 8);
  for (int t = 0; t < 16; ++t) {
    __syncthreads();
    *(short8*)&Als[abase ^ aswz] = a0;
    *(short8*)&Als[(abase + 8) ^ aswz] = a1;
    *(short8*)&Bls[abase ^ aswz] = b0;
    *(short8*)&Bls[(abase + 8) ^ aswz] = b1;
    __syncthreads();
    if (t + 1 < 16) {
      const short* an = aseg + (t + 1) * 64;
      const short* bn = bseg + (t + 1) * 64;
      a0 = *(const short8*)(an);
      a1 = *(const short8*)(an + 8);
      b0 = *(const short8*)(bn);
      b1 = *(const short8*)(bn + 8);
    }
#pragma unroll
    for (int kk = 0; kk < 2; ++kk) {
      short8 af[2], bf[2];
#pragma unroll
      for (int f = 0; f < 2; ++f) {
        int ar = wm + f * 16 + lr;
        af[f] = *(short8*)&Als[(ar * 64 + kk * 32 + kg * 8) ^ ((ar & 7) * 8)];
        int br = wn + f * 16 + lr;
        bf[f] = *(short8*)&Bls[(br * 64 + kk * 32 + kg * 8) ^ ((br & 7) * 8)];
      }
#pragma unroll
      for (int fi = 0; fi < 2; ++fi)
#pragma unroll
        for (int fj = 0; fj < 2; ++fj)
          acc[fi][fj] = __builtin_amdgcn_mfma_f32_16x16x32_bf16(
              af[fi], bf[fj], acc[fi][fj], 0, 0, 0);
    }
  }
  int rg = lane >> 4;
#pragma unroll
  for (int fi = 0; fi < 2; ++fi)
#pragma unroll
    for (int fj = 0; fj < 2; ++fj)
#pragma unroll
      for (int r = 0; r < 4; ++r) {
        int gm = m0 + wm + fi * 16 + rg * 4 + r;
        int gn = n0 + wn + fj * 16 + lr;
        out[(long)gm * 1024 + gn] = acc[fi][fj][r];
      }
}

// ---- RoPE + fused 3-way splits (q,ik) + bf16 K copy ------------------------
__global__ void rope_kernel(float* __restrict__ q, float* __restrict__ k,
                            float* __restrict__ ik, short* __restrict__ k_bf,
                            short* __restrict__ qh, short* __restrict__ qm,
                            short* __restrict__ ql, short* __restrict__ ikh,
                            short* __restrict__ ikm, short* __restrict__ ikl,
                            int big,
                            const float* __restrict__ cosb,
                            const float* __restrict__ sinb) {
  int gid = blockIdx.x * 256 + threadIdx.x;
  const int NV = SEQ * (NH + NKV + 1);
  if (gid >= NV * 32) return;
  int p = gid & 31;
  int vec = gid >> 5;
  int s;
  if (vec < SEQ * NH) {                     // q branch
    s = vec / NH; int h = vec % NH;
    long off = (long)s * 1024 + h * 64;
    float c = cosb[s * 64 + p], sn = sinb[s * 64 + p];
    float x1 = q[off + p], x2 = q[off + p + 32];
    float y1 = x1 * c - x2 * sn;
    float y2 = x2 * c + x1 * sn;
    q[off + p] = y1;
    q[off + p + 32] = y2;
    if (big) {
      short h1, m1, l1, h2, m2, l2;
      split3(y1, h1, m1, l1);
      split3(y2, h2, m2, l2);
      qh[off + p] = h1; qm[off + p] = m1; ql[off + p] = l1;
      qh[off + p + 32] = h2; qm[off + p + 32] = m2; ql[off + p + 32] = l2;
    }
  } else if (vec < SEQ * (NH + NKV)) {      // k branch (+ bf16 copy)
    int t = vec - SEQ * NH;
    s = t / NKV; int kh = t % NKV;
    long off = (long)s * 256 + kh * 64;
    float c = cosb[s * 64 + p], sn = sinb[s * 64 + p];
    float x1 = k[off + p], x2 = k[off + p + 32];
    float y1 = x1 * c - x2 * sn;
    float y2 = x2 * c + x1 * sn;
    k[off + p] = y1;
    k[off + p + 32] = y2;
    k_bf[off + p] = f2bf_bits(y1);
    k_bf[off + p + 32] = f2bf_bits(y2);
  } else {                                  // ik branch (+ splits)
    s = vec - SEQ * (NH + NKV);
    long off = (long)s * 64;
    float c = cosb[s * 64 + p], sn = sinb[s * 64 + p];
    float x1 = ik[off + p], x2 = ik[off + p + 32];
    float y1 = x1 * c - x2 * sn;
    float y2 = x2 * c + x1 * sn;
    ik[off + p] = y1;
    ik[off + p + 32] = y2;
    if (big) {
      short h1, m1, l1, h2, m2, l2;
      split3(y1, h1, m1, l1);
      split3(y2, h2, m2, l2);
      ikh[off + p] = h1; ikm[off + p] = m1; ikl[off + p] = l1;
      ikh[off + p + 32] = h2; ikm[off + p + 32] = m2; ikl[off + p + 32] = l2;
    }
  }
}

// ---- MFMA indexer scores, EXACT 3-way split; next-h q prefetched to regs ---
__global__ __launch_bounds__(256) void idx_mfma6(
    const short* __restrict__ q_h, const short* __restrict__ q_m,
    const short* __restrict__ q_l, const short* __restrict__ ik_h,
    const short* __restrict__ ik_m, const short* __restrict__ ik_l,
    const float* __restrict__ wb, float* __restrict__ sc) {
  int b = blockIdx.x;                         // 0..527 triangular
  int tq = (int)((sqrtf(8.f * b + 1.f) - 1.f) * 0.5f);
  while ((tq * (tq + 1)) / 2 > b) --tq;
  while (((tq + 1) * (tq + 2)) / 2 <= b) ++tq;
  int tk = b - (tq * (tq + 1)) / 2;
  int q0 = tq * 64, k0 = tk * 64;

  __shared__ short QH[64 * 64] __attribute__((aligned(16)));
  __shared__ short QM[64 * 64] __attribute__((aligned(16)));
  __shared__ short QL[64 * 64] __attribute__((aligned(16)));
  __shared__ short IH[64 * 64] __attribute__((aligned(16)));
  __shared__ short IM[64 * 64] __attribute__((aligned(16)));
  __shared__ short IL[64 * 64] __attribute__((aligned(16)));
  __shared__ float wls[64][17];

  int tid = threadIdx.x;
  int lane = tid & 63, wid = tid >> 6;
  int wm = (wid >> 1) * 32, wn = (wid & 1) * 32;
  int lr = lane & 15, kg = lane >> 4;
  int sr = tid >> 2, seg = tid & 3;
  int sbase = sr * 64 + seg * 16;
  int sswz = (sr & 7) * 8;

  {  // stage ik tiles (once) + w tile
    const short* g0 = ik_h + (long)(k0 + sr) * 64 + seg * 16;
    const short* g1 = ik_m + (long)(k0 + sr) * 64 + seg * 16;
    const short* g2 = ik_l + (long)(k0 + sr) * 64 + seg * 16;
#pragma unroll
    for (int c = 0; c < 2; ++c) {
      *(short8*)&IH[(sbase + c * 8) ^ sswz] = *(const short8*)(g0 + c * 8);
      *(short8*)&IM[(sbase + c * 8) ^ sswz] = *(const short8*)(g1 + c * 8);
      *(short8*)&IL[(sbase + c * 8) ^ sswz] = *(const short8*)(g2 + c * 8);
    }
    int wlc = tid & 15, wlr = tid >> 4;
#pragma unroll
    for (int i = 0; i < 4; ++i)
      wls[wlr + 16 * i][wlc] = wb[(long)(q0 + wlr + 16 * i) * 16 + wlc] * 0.25f;
  }
  long qrow = (long)(q0 + sr) * 1024 + seg * 16;
  short8 pa0 = *(const short8*)(q_h + qrow);
  short8 pa1 = *(const short8*)(q_h + qrow + 8);
  short8 pb0 = *(const short8*)(q_m + qrow);
  short8 pb1 = *(const short8*)(q_m + qrow + 8);
  short8 pc0 = *(const short8*)(q_l + qrow);
  short8 pc1 = *(const short8*)(q_l + qrow + 8);
  __syncthreads();
  short8 bh[2][2], bm_[2][2], bl_[2][2];
#pragma unroll
  for (int fj = 0; fj < 2; ++fj)
#pragma unroll
    for (int ks = 0; ks < 2; ++ks) {
      int br = wn + fj * 16 + lr;
      int idx = (br * 64 + ks * 32 + kg * 8) ^ ((br & 7) * 8);
      bh[fj][ks] = *(short8*)&IH[idx];
      bm_[fj][ks] = *(short8*)&IM[idx];
      bl_[fj][ks] = *(short8*)&IL[idx];
    }

  int rg = lane >> 4;
  f32x4 acc[2][2] = {};
  for (int h = 0; h < NH; ++h) {
    __syncthreads();                       // prior h's A-frag reads done
    *(short8*)&QH[sbase ^ sswz] = pa0;
    *(short8*)&QH[(sbase + 8) ^ sswz] = pa1;
    *(short8*)&QM[sbase ^ sswz] = pb0;
    *(short8*)&QM[(sbase + 8) ^ sswz] = pb1;
    *(short8*)&QL[sbase ^ sswz] = pc0;
    *(short8*)&QL[(sbase + 8) ^ sswz] = pc1;
    if (h + 1 < NH) {                      // prefetch next h (hidden by MFMA)
      long nrow = qrow + (h + 1) * 64;
      pa0 = *(const short8*)(q_h + nrow);
      pa1 = *(const short8*)(q_h + nrow + 8);
      pb0 = *(const short8*)(q_m + nrow);
      pb1 = *(const short8*)(q_m + nrow + 8);
      pc0 = *(const short8*)(q_l + nrow);
      pc1 = *(const short8*)(q_l + nrow + 8);
    }
    __syncthreads();
    f32x4 dot[2][2] = {};
#pragma unroll
    for (int ks = 0; ks < 2; ++ks) {
      short8 ah[2], am[2], al[2];
#pragma unroll
      for (int fi = 0; fi < 2; ++fi) {
        int ar = wm + fi * 16 + lr;
        int idx = (ar * 64 + ks * 32 + kg * 8) ^ ((ar & 7) * 8);
        ah[fi] = *(short8*)&QH[idx];
        am[fi] = *(short8*)&QM[idx];
        al[fi] = *(short8*)&QL[idx];
      }
#pragma unroll
      for (int fi = 0; fi < 2; ++fi)
#pragma unroll
        for (int fj = 0; fj < 2; ++fj) {
          dot[fi][fj] = __builtin_amdgcn_mfma_f32_16x16x32_bf16(
              ah[fi], bh[fj][ks], dot[fi][fj], 0, 0, 0);      // hh
          dot[fi][fj] = __builtin_amdgcn_mfma_f32_16x16x32_bf16(
              ah[fi], bm_[fj][ks], dot[fi][fj], 0, 0, 0);     // hm
          dot[fi][fj] = __builtin_amdgcn_mfma_f32_16x16x32_bf16(
              am[fi], bh[fj][ks], dot[fi][fj], 0, 0, 0);      // mh
          dot[fi][fj] = __builtin_amdgcn_mfma_f32_16x16x32_bf16(
              ah[fi], bl_[fj][ks], dot[fi][fj], 0, 0, 0);     // hl
          dot[fi][fj] = __builtin_amdgcn_mfma_f32_16x16x32_bf16(
              am[fi], bm_[fj][ks], dot[fi][fj], 0, 0, 0);     // mm
          dot[fi][fj] = __builtin_amdgcn_mfma_f32_16x16x32_bf16(
              al[fi], bh[fj][ks], dot[fi][fj], 0, 0, 0);      // lh
        }
    }
#pragma unroll
    for (int fi = 0; fi < 2; ++fi) {
      float wv[4];
#pragma unroll
      for (int r = 0; r < 4; ++r) wv[r] = wls[wm + fi * 16 + rg * 4 + r][h];
#pragma unroll
      for (int fj = 0; fj < 2; ++fj)
#pragma unroll
        for (int r = 0; r < 4; ++r)
          acc[fi][fj][r] += fmaxf(dot[fi][fj][r], 0.f) * wv[r];
    }
  }
#pragma unroll
  for (int fi = 0; fi < 2; ++fi)
#pragma unroll
    for (int fj = 0; fj < 2; ++fj)
#pragma unroll
      for (int r = 0; r < 4; ++r) {
        int q = q0 + wm + fi * 16 + rg * 4 + r;
        int k = k0 + wn + fj * 16 + lr;
        if (k <= q) sc[(long)q * (q + 1) / 2 + k] = acc[fi][fj][r];
      }
}

// ---- fallback VALU indexer (if ws too small for splits) --------------------
__global__ __launch_bounds__(256) void idx_scores(
    const float* __restrict__ qb, const float* __restrict__ ikb,
    const float* __restrict__ wb, float* __restrict__ sc) {
  int b = blockIdx.x;
  int tq = (int)((sqrtf(8.f * b + 1.f) - 1.f) * 0.5f);
  while ((tq * (tq + 1)) / 2 > b) --tq;
  while (((tq + 1) * (tq + 2)) / 2 <= b) ++tq;
  int tk = b - (tq * (tq + 1)) / 2;
  int q0 = tq * 64, k0 = tk * 64;
  __shared__ float As0[64][68];
  __shared__ float As1[64][68];
  __shared__ float Bs[64][68];
  __shared__ float wls[64][17];
  int tid = threadIdx.x;
  int lc = tid & 15, lr = tid >> 4;
  int tx = lc, ty = lr;
#pragma unroll
  for (int c = 0; c < 4; ++c) {
    int d = c * 16 + lc;
#pragma unroll
    for (int i = 0; i < 4; ++i)
      Bs[d][lr + 16 * i] = ikb[(long)(k0 + lr + 16 * i) * 64 + d];
  }
#pragma unroll
  for (int i = 0; i < 4; ++i)
    wls[lr + 16 * i][lc] = wb[(long)(q0 + lr + 16 * i) * 16 + lc] * 0.25f;
  float pf0[16], pf1[16];
#pragma unroll
  for (int c = 0; c < 4; ++c)
#pragma unroll
    for (int i = 0; i < 4; ++i) {
      long base = (long)(q0 + lr + 16 * i) * 1024 + c * 16 + lc;
      pf0[c * 4 + i] = qb[base];
      pf1[c * 4 + i] = qb[base + 64];
    }
  float acc[4][4] = {};
  for (int hp = 0; hp < 8; ++hp) {
    __syncthreads();
#pragma unroll
    for (int c = 0; c < 4; ++c)
#pragma unroll
      for (int i = 0; i < 4; ++i) {
        As0[c * 16 + lc][lr + 16 * i] = pf0[c * 4 + i];
        As1[c * 16 + lc][lr + 16 * i] = pf1[c * 4 + i];
      }
    if (hp < 7) {
#pragma unroll
      for (int c = 0; c < 4; ++c)
#pragma unroll
        for (int i = 0; i < 4; ++i) {
          long base =
              (long)(q0 + lr + 16 * i) * 1024 + (2 * hp + 2) * 64 + c * 16 + lc;
          pf0[c * 4 + i] = qb[base];
          pf1[c * 4 + i] = qb[base + 64];
        }
    }
    __syncthreads();
    float wv0[4], wv1[4];
#pragma unroll
    for (int i = 0; i < 4; ++i) {
      wv0[i] = wls[ty * 4 + i][2 * hp];
      wv1[i] = wls[ty * 4 + i][2 * hp + 1];
    }
    float dot0[4][4] = {}, dot1[4][4] = {};
#pragma unroll
    for (int kk = 0; kk < 64; ++kk) {
      float4 a0 = *(const float4*)&As0[kk][ty * 4];
      float4 a1 = *(const float4*)&As1[kk][ty * 4];
      float4 b4 = *(const float4*)&Bs[kk][tx * 4];
      float av0[4] = {a0.x, a0.y, a0.z, a0.w};
      float av1[4] = {a1.x, a1.y, a1.z, a1.w};
      float bv[4] = {b4.x, b4.y, b4.z, b4.w};
#pragma unroll
      for (int i = 0; i < 4; ++i)
#pragma unroll
        for (int j = 0; j < 4; ++j) {
          dot0[i][j] += av0[i] * bv[j];
          dot1[i][j] += av1[i] * bv[j];
        }
    }
#pragma unroll
    for (int i = 0; i < 4; ++i)
#pragma unroll
      for (int j = 0; j < 4; ++j) {
        acc[i][j] += fmaxf(dot0[i][j], 0.f) * wv0[i];
        acc[i][j] += fmaxf(dot1[i][j], 0.f) * wv1[i];
      }
  }
#pragma unroll
  for (int i = 0; i < 4; ++i) {
    int q = q0 + ty * 4 + i;
    long base = (long)q * (q + 1) / 2;
#pragma unroll
    for (int j = 0; j < 4; ++j) {
      int k = k0 + tx * 4 + j;
      if (k <= q) sc[base + k] = acc[i][j];
    }
  }
}

// ---- exact top-128 per row, one wave per row -------------------------------
__device__ inline unsigned fkey(float f) {
  unsigned u = __float_as_uint(f);
  return (u & 0x80000000u) ? ~u : (u | 0x80000000u);
}

__global__ __launch_bounds__(64) void topk_rows(
    const float* __restrict__ sc, int* __restrict__ tidx,
    int* __restrict__ tcnt) {
  int qi = blockIdx.x;
  int lane = threadIdx.x;
  if (qi < TOPK) {
    for (int i = lane; i <= qi; i += 64) tidx[(long)qi * TOPK + i] = i;
    if (lane == 0) tcnt[qi] = qi + 1;
    return;
  }
  const float* row = sc + (long)qi * (qi + 1) / 2;
  unsigned keys[32];
#pragma unroll
  for (int i = 0; i < 32; ++i) {
    int k = lane + 64 * i;
    keys[i] = (k <= qi) ? fkey(row[k] + 0.f) : 0u;
  }
  unsigned lo = 0u, hi = 0xFFFFFFFEu;
  while (lo < hi) {
    unsigned mid = lo + ((hi - lo + 1) >> 1);
    int cnt = 0;
#pragma unroll
    for (int i = 0; i < 32; ++i) cnt += (keys[i] >= mid) ? 1 : 0;
    for (int off = 32; off; off >>= 1) cnt += __shfl_xor(cnt, off);
    if (cnt >= TOPK) lo = mid; else hi = mid - 1;
  }
  unsigned T = lo;
  __shared__ int c1;
  if (lane == 0) c1 = 0;
  __syncthreads();
#pragma unroll
  for (int i = 0; i < 32; ++i) {
    if (keys[i] > T) {
      int pos = atomicAdd(&c1, 1);
      tidx[(long)qi * TOPK + pos] = lane + 64 * i;
    }
  }
  __syncthreads();
  int c = c1;
  for (int i = 0; i < 32 && c < TOPK; ++i) {
    unsigned long long m = __ballot(keys[i] == T);
    while (m && c < TOPK) {
      int l = __ffsll(m) - 1;
      m &= m - 1;
      if (lane == 0) tidx[(long)qi * TOPK + c] = 64 * i + l;
      ++c;
    }
  }
  if (lane == 0) tcnt[qi] = TOPK;
}

// ---- sparse attention: block (q, kvh); 4 waves; MFMA QK^T ------------------
// A = gathered K rows (bf16, XOR-swizzled LDS), B = 4 heads' q (bf16).
// Wave w computes keys [32w, 32w+32) for all 4 heads: 4 MFMAs replace the
// per-lane VALU dot (~256 inst). Logits -> sl[4][128]; softmax/PV unchanged.
__global__ __launch_bounds__(256) void sparse_attn(
    const float* __restrict__ qb, const short* __restrict__ kb_bf,
    const float* __restrict__ vb, const int* __restrict__ tidx,
    const int* __restrict__ tcnt, short* __restrict__ attn) {
  int kvh = blockIdx.x;
  int qi  = blockIdx.y;
  int tid = threadIdx.x, lane = tid & 63, w = tid >> 6;
  int cnt = tcnt[qi];
  __shared__ int   idxs[128];
  __shared__ short Ks[128 * 64] __attribute__((aligned(16)));
  __shared__ short qs_bf[4][64] __attribute__((aligned(16)));
  __shared__ float sl[4][128];          // logits, then reused for probs
  if (tid < 128) idxs[tid] = (tid < cnt) ? tidx[(long)qi * TOPK + tid] : 0;
  qs_bf[tid >> 6][tid & 63] = f2bf_bits(
      qb[(long)qi * 1024 + (kvh * 4 + (tid >> 6)) * 64 + (tid & 63)]);
  __syncthreads();
  {
    int j0 = tid >> 2, qf = tid & 3;     // 4 threads per K row (coalesced)
#pragma unroll
    for (int pass = 0; pass < 2; ++pass) {
      int j = j0 + pass * 64;
      if (j < cnt) {
        int ki = idxs[j];
        const short* kr = kb_bf + (long)ki * 256 + kvh * 64 + qf * 16;
        short8 k0 = *(const short8*)(kr);
        short8 k1 = *(const short8*)(kr + 8);
        int swz = (j & 7) * 8;
        *(short8*)&Ks[(j * 64 + qf * 16) ^ swz] = k0;
        *(short8*)&Ks[(j * 64 + qf * 16 + 8) ^ swz] = k1;
      }
    }
  }
  __syncthreads();
  int lr = lane & 15, kg = lane >> 4;
  // B fragments: col = lr -> head (valid lr<4; duplicates otherwise, unused)
  short8 bq0 = *(const short8*)&qs_bf[lr & 3][kg * 8];
  short8 bq1 = *(const short8*)&qs_bf[lr & 3][32 + kg * 8];
  f32x4 dt[2] = {};
#pragma unroll
  for (int t2 = 0; t2 < 2; ++t2) {
    int row = w * 32 + t2 * 16 + lr;
    int rswz = (row & 7) * 8;
    short8 a0 = *(short8*)&Ks[(row * 64 + kg * 8) ^ rswz];
    short8 a1 = *(short8*)&Ks[(row * 64 + 32 + kg * 8) ^ rswz];
    dt[t2] = __builtin_amdgcn_mfma_f32_16x16x32_bf16(a0, bq0, dt[t2], 0, 0, 0);
    dt[t2] = __builtin_amdgcn_mfma_f32_16x16x32_bf16(a1, bq1, dt[t2], 0, 0, 0);
  }
  // C layout: col = lane&15 (head), row-in-tile = (lane>>4)*4 + r (key)
  if (lr < 4) {
#pragma unroll
    for (int t2 = 0; t2 < 2; ++t2)
#pragma unroll
      for (int r = 0; r < 4; ++r)
        sl[lr][w * 32 + t2 * 16 + kg * 4 + r] = dt[t2][r] * 0.125f;
  }
  __syncthreads();                        // sl row w has writes from all waves
  float l0 = (lane < cnt) ? sl[w][lane] : -INFINITY;
  float l1 = (lane + 64 < cnt) ? sl[w][lane + 64] : -INFINITY;
  float m = fmaxf(l0, l1);
  for (int off = 32; off; off >>= 1) m = fmaxf(m, __shfl_xor(m, off));
  float p0 = expf(l0 - m), p1 = expf(l1 - m);
  float ssum = p0 + p1;
  for (int off = 32; off; off >>= 1) ssum += __shfl_xor(ssum, off);
  sl[w][lane] = p0;                       // row w owned by wave w from here
  sl[w][lane + 64] = p1;
  __syncthreads();
  int sub = lane >> 4, quad = lane & 15;
  float4 o4 = {0.f, 0.f, 0.f, 0.f};
#pragma unroll 4
  for (int j = sub; j < cnt; j += 4) {
    int ki = idxs[j];
    float p = sl[w][j];
    float4 vv = *(const float4*)(vb + (long)ki * 256 + kvh * 64 + quad * 4);
    o4.x += p * vv.x; o4.y += p * vv.y;
    o4.z += p * vv.z; o4.w += p * vv.w;
  }
#pragma unroll
  for (int off = 16; off <= 32; off <<= 1) {
    o4.x += __shfl_xor(o4.x, off);
    o4.y += __shfl_xor(o4.y, off);
    o4.z += __shfl_xor(o4.z, off);
    o4.w += __shfl_xor(o4.w, off);
  }
  if (sub == 0) {
    float inv = 1.f / ssum;
    short4 ov;
    ov.x = f2bf_bits(o4.x * inv); ov.y = f2bf_bits(o4.y * inv);
    ov.z = f2bf_bits(o4.z * inv); ov.w = f2bf_bits(o4.w * inv);
    *(short4*)&attn[(long)qi * 1024 + (kvh * 4 + w) * 64 + quad * 4] = ov;
  }
}

// ---- f32 -> bf16 (hi only), fallback path for Wo ---------------------------
__global__ __launch_bounds__(256) void conv_hi(
    const float* __restrict__ src, short* __restrict__ dst, int n4) {
  int i = blockIdx.x * 256 + threadIdx.x;
  if (i >= n4) return;
  float4 v = *(const float4*)(src + (long)i * 4);
  short4 hv;
  hv.x = f2bf_bits(v.x); hv.y = f2bf_bits(v.y);
  hv.z = f2bf_bits(v.z); hv.w = f2bf_bits(v.w);
  *(short4*)&dst[(long)i * 4] = hv;
}

// ---------------------------------------------------------------------------
extern "C" void kernel_launch(void* const* d_in, const int* in_sizes, int n_in,
                              void* d_out, int out_size, void* d_ws,
                              size_t ws_size, hipStream_t stream) {
  const float* hs   = (const float*)d_in[0];
  const float* cosb = (const float*)d_in[1];
  const float* sinb = (const float*)d_in[2];
  const float* Wq   = (const float*)d_in[3];
  const float* bq   = (const float*)d_in[4];
  const float* Wk   = (const float*)d_in[5];
  const float* bk   = (const float*)d_in[6];
  const float* Wv   = (const float*)d_in[7];
  const float* bv   = (const float*)d_in[8];
  const float* Wo   = (const float*)d_in[9];
  const float* Wik  = (const float*)d_in[10];
  const float* bik  = (const float*)d_in[11];
  const float* Wiw  = (const float*)d_in[12];
  const float* biw  = (const float*)d_in[13];
  float* out = (float*)d_out;

  float* ws = (float*)d_ws;
  float* qb   = ws;  ws += (long)SEQ * 1024;
  float* kb   = ws;  ws += (long)SEQ * 256;
  float* vb   = ws;  ws += (long)SEQ * 256;
  float* ikb  = ws;  ws += (long)SEQ * 64;
  float* wb   = ws;  ws += (long)SEQ * 16;
  int* tidx   = (int*)ws;  ws += (long)SEQ * TOPK;
  int* tcnt   = (int*)ws;  ws += SEQ;
  short* kb_bf = (short*)ws; ws += (long)SEQ * 128;   // S x 256 bf16 = 1 MB
  float* R1   = ws;  ws += (long)SEQ * (SEQ + 1) / 2;
  float* R2   = ws;  ws += (long)1104 * 1024;
  float* R3   = ws;  ws += 3L * SEQ * 512;            // q_h/m/l splits
  float* R4   = ws;  ws += (long)512 * 1024;          // Wo_bf2: 1024x1024 bf16
  size_t need_big = (size_t)(ws - (float*)d_ws) * 4;  // ~42.8 MB
  int big = ws_size >= need_big;

  short* A_cat   = (short*)R1;          // 8 MB (dead before scores)
  float* scores  = R1;
  short* Wh      = (short*)R2;
  short* Wl      = Wh + (long)1104 * 1024;
  short* attn_bf = (short*)R2;          // Wh/Wl dead by then
  short* Wkv_bf  = (short*)tidx;        // dead before tidx written
  short* Wo_bf2  = (short*)R4;          // dedicated (big path)
  short* Wo_bf_s = (short*)qb;          // fallback alias (small path)
  short* q_h     = (short*)R3;          // 4 MB each
  short* q_m     = q_h + (long)SEQ * 1024;
  short* q_l     = q_m + (long)SEQ * 1024;
  short* ik_h    = (short*)tidx;        // 3 x 256KB <= 1MB
  short* ik_m    = ik_h + (long)SEQ * 64;
  short* ik_l    = ik_m + (long)SEQ * 64;

  dim3 blk(256);
  // big path: convert Wo up-front inside conv_all (removes a tail dispatch)
  int conv_blocks = big ? 4688 : 3664;
  conv_all<<<conv_blocks, blk, 0, stream>>>(hs, Wq, Wik, Wiw, Wk, Wv, Wo,
                                            A_cat, Wh, Wl, Wkv_bf, Wo_bf2);
  gemm_all<<<dim3(26, 32), blk, 0, stream>>>(A_cat, Wh, Wl, Wkv_bf, bq, bik,
                                             biw, bk, bv, qb, ikb, wb, kb, vb);

  int nrope = SEQ * (NH + NKV + 1) * 32;
  rope_kernel<<<(nrope + 255) / 256, blk, 0, stream>>>(
      qb, kb, ikb, kb_bf, q_h, q_m, q_l, ik_h, ik_m, ik_l, big, cosb, sinb);

  if (big) {
    idx_mfma6<<<528, blk, 0, stream>>>(q_h, q_m, q_l, ik_h, ik_m, ik_l, wb,
                                       scores);
  } else {
    idx_scores<<<528, blk, 0, stream>>>(qb, ikb, wb, scores);
  }
  topk_rows<<<SEQ, dim3(64), 0, stream>>>(scores, tidx, tcnt);

  sparse_attn<<<dim3(NKV, SEQ), blk, 0, stream>>>(qb, kb_bf, vb, tidx, tcnt,
                                                  attn_bf);

  if (big) {
    gemm_wo<<<dim3(16, 32), blk, 0, stream>>>(attn_bf, Wo_bf2, out);
  } else {
    conv_hi<<<1024, blk, 0, stream>>>(Wo, Wo_bf_s, 1024 * 256);
    gemm_wo<<<dim3(16, 32), blk, 0, stream>>>(attn_bf, Wo_bf_s, out);
  }
}